// Round 2
// baseline (1223.234 us; speedup 1.0000x reference)
//
#include <hip/hip_runtime.h>

constexpr int N_NODES = 50000;
constexpr int N_REL   = 4;
constexpr int EMBD    = 128;
constexpr int N_HEAD  = 4;
constexpr int HS      = 32;
constexpr int N_EDGE  = 400000;

// P[r][n][j] = sum_k W[r][h(j)][s(j)][k] * x[n][h*32+k],  j = h*32+s
// Block: 64 nodes x 128 outputs, 256 threads. Thread t -> (j = t&127, node-half = t>>7).
// Weights for this thread's (h,s) held in 32 VGPRs; x tile staged in LDS
// (reads are wave-broadcast -> conflict-free). Stores coalesced (lanes = consecutive j).
template<bool DUAL>
__global__ __launch_bounds__(256) void proj_kernel(
    const float* __restrict__ x,
    const float* __restrict__ W1,
    const float* __restrict__ W2,
    float* __restrict__ P1, float* __restrict__ P2)
{
    const int r    = blockIdx.y;
    const int n0   = blockIdx.x * 64;
    const int t    = threadIdx.x;
    const int j    = t & 127;
    const int half = t >> 7;
    const int h    = j >> 5;
    const int s    = j & 31;

    __shared__ float xs[64 * 128];
    {
        const float4* x4 = (const float4*)(x + (size_t)n0 * 128);
        float4* xs4 = (float4*)xs;
        for (int idx = t; idx < 64 * 32; idx += 256) {       // 32 float4 per node-row
            int n = n0 + (idx >> 5);
            float4 v = make_float4(0.f, 0.f, 0.f, 0.f);
            if (n < N_NODES) v = x4[idx];
            xs4[idx] = v;
        }
    }

    float w1[32], w2[32];
    {
        const float* w1p = W1 + (((r * N_HEAD + h) * HS + s) * HS);
        #pragma unroll
        for (int k = 0; k < 32; k++) w1[k] = w1p[k];
        if (DUAL) {
            const float* w2p = W2 + (((r * N_HEAD + h) * HS + s) * HS);
            #pragma unroll
            for (int k = 0; k < 32; k++) w2[k] = w2p[k];
        }
    }
    __syncthreads();

    #pragma unroll 1
    for (int i = 0; i < 32; i++) {
        int n = n0 + half * 32 + i;
        if (n >= N_NODES) break;               // uniform within wave
        const float* xp = &xs[(half * 32 + i) * 128 + h * 32];
        float a1 = 0.f, a2 = 0.f;
        #pragma unroll
        for (int k = 0; k < 32; k++) {
            float xv = xp[k];
            a1 += w1[k] * xv;
            if (DUAL) a2 += w2[k] * xv;
        }
        size_t o = ((size_t)r * N_NODES + n) * 128 + j;
        P1[o] = a1;
        if (DUAL) P2[o] = a2;
    }
}

// UT[r][j][i] = unify[r][i][j]  (256 KB fp32, stays hot in L2).
__global__ __launch_bounds__(256) void transpose_u(
    const float* __restrict__ U, float* __restrict__ UT)
{
    int idx = blockIdx.x * 256 + threadIdx.x;          // r*16384 + i*128 + j
    int r = idx >> 14, rem = idx & 16383, i = rem >> 7, jj = rem & 127;
    UT[(r * 128 + jj) * 128 + i] = U[idx];
}

// One thread per (edge, head): dot(K[pred,sub,h,:], Q[pred,obj,h,:]),
// exp WITHOUT max-subtraction (analytically identical; dot bounded ~±12, fp32-exp safe).
__global__ __launch_bounds__(256) void edge_dot_kernel(
    const int* __restrict__ esub, const int* __restrict__ epred, const int* __restrict__ eobj,
    const float* __restrict__ K, const float* __restrict__ Q,
    float* __restrict__ EX, float* __restrict__ SEG)
{
    int gid = blockIdx.x * 256 + threadIdx.x;          // exact: 6250*256 == E*H
    int e = gid >> 2, h = gid & 3;
    int pred = epred[e], sub = esub[e], obj = eobj[e];
    const float4* kp = (const float4*)(K + ((size_t)pred * N_NODES + sub) * 128 + h * 32);
    const float4* qp = (const float4*)(Q + ((size_t)pred * N_NODES + obj) * 128 + h * 32);
    float dot = 0.f;
    #pragma unroll
    for (int k = 0; k < 8; k++) {
        float4 a = kp[k], b = qp[k];
        dot += a.x * b.x + a.y * b.y + a.z * b.z + a.w * b.w;
    }
    float ex = __expf(dot);
    EX[gid] = ex;
    atomicAdd(&SEG[(pred * N_NODES + sub) * 4 + h], ex);
}

// 128 threads per edge: AGG[row][idx] += (EX/SEG) * V[pred,obj,idx]
__global__ __launch_bounds__(256) void edge_agg_kernel(
    const int* __restrict__ esub, const int* __restrict__ epred, const int* __restrict__ eobj,
    const float* __restrict__ V, const float* __restrict__ EX, const float* __restrict__ SEG,
    float* __restrict__ AGG)
{
    long long gid = (long long)blockIdx.x * 256 + threadIdx.x;  // exact: 200000*256 == E*128
    int e   = (int)(gid >> 7);
    int idx = (int)(gid & 127);
    int h   = idx >> 5;
    int pred = epred[e], sub = esub[e], obj = eobj[e];
    int row = pred * N_NODES + sub;
    float att = EX[e * 4 + h] / SEG[row * 4 + h];
    float v = V[((size_t)pred * N_NODES + obj) * 128 + idx];
    atomicAdd(&AGG[(size_t)row * 128 + idx], att * v);
}

// out[n][i] = relu( sum_r sum_j UT[r][j][i] * AGG[r][n][j] )
// Thread t: node n = blk*32 + t/8, i-chunk c = t&7 (16 outputs). UT float4 reads are
// L2-hot; AGG scalar reads broadcast across the 8 i-chunk lanes of a node.
__global__ __launch_bounds__(256) void unify_kernel(
    const float* __restrict__ AGG, const float* __restrict__ UT, float* __restrict__ out)
{
    int t = threadIdx.x;
    int c = t & 7;
    int n = blockIdx.x * 32 + (t >> 3);
    if (n >= N_NODES) return;

    float acc[16];
    #pragma unroll
    for (int k = 0; k < 16; k++) acc[k] = 0.f;

    for (int r = 0; r < 4; r++) {
        const float* ag = AGG + ((size_t)r * N_NODES + n) * 128;
        const float* up = UT + r * 16384 + c * 16;
        #pragma unroll 4
        for (int jj = 0; jj < 128; jj++) {
            float a = ag[jj];
            const float4* u4 = (const float4*)(up + (size_t)jj * 128);
            float4 u0 = u4[0], u1 = u4[1], u2 = u4[2], u3 = u4[3];
            acc[0]  += a * u0.x; acc[1]  += a * u0.y; acc[2]  += a * u0.z; acc[3]  += a * u0.w;
            acc[4]  += a * u1.x; acc[5]  += a * u1.y; acc[6]  += a * u1.z; acc[7]  += a * u1.w;
            acc[8]  += a * u2.x; acc[9]  += a * u2.y; acc[10] += a * u2.z; acc[11] += a * u2.w;
            acc[12] += a * u3.x; acc[13] += a * u3.y; acc[14] += a * u3.z; acc[15] += a * u3.w;
        }
    }

    float4* op = (float4*)(out + (size_t)n * 128 + c * 16);
    #pragma unroll
    for (int q = 0; q < 4; q++) {
        op[q] = make_float4(fmaxf(acc[4*q+0], 0.f), fmaxf(acc[4*q+1], 0.f),
                            fmaxf(acc[4*q+2], 0.f), fmaxf(acc[4*q+3], 0.f));
    }
}

extern "C" void kernel_launch(void* const* d_in, const int* in_sizes, int n_in,
                              void* d_out, int out_size, void* d_ws, size_t ws_size,
                              hipStream_t stream)
{
    const float* x  = (const float*)d_in[0];
    const float* tk = (const float*)d_in[1];
    const float* tq = (const float*)d_in[2];
    const float* tv = (const float*)d_in[3];
    const float* un = (const float*)d_in[4];
    const int* esub  = (const int*)d_in[5];
    const int* epred = (const int*)d_in[6];
    const int* eobj  = (const int*)d_in[7];
    float* out = (float*)d_out;

    // Workspace layout (bytes), total ~214.7 MB:
    //   B1: [R][N][128] fp32  (K, later zeroed -> AGG)     @ 0          (102,400,000)
    //   B2: [R][N][128] fp32  (Q, later overwritten by V)  @ 102400000  (102,400,000)
    //   EX: [E][H]      fp32                               @ 204800000  (  6,400,000)
    //   SEG:[R*N][H]    fp32                               @ 211200000  (  3,200,000)
    //   UT: [R][128][128] fp32                             @ 214400000  (    262,144)
    char* ws = (char*)d_ws;
    float* B1  = (float*)(ws);
    float* B2  = (float*)(ws + 102400000);
    float* EX  = (float*)(ws + 204800000);
    float* SEG = (float*)(ws + 211200000);
    float* UT  = (float*)(ws + 214400000);

    hipMemsetAsync(SEG, 0, (size_t)N_REL * N_NODES * N_HEAD * sizeof(float), stream);

    dim3 pg((N_NODES + 63) / 64, N_REL);
    proj_kernel<true><<<pg, 256, 0, stream>>>(x, tk, tq, B1, B2);   // K -> B1, Q -> B2
    transpose_u<<<(N_REL * EMBD * EMBD) / 256, 256, 0, stream>>>(un, UT);

    edge_dot_kernel<<<(N_EDGE * N_HEAD) / 256, 256, 0, stream>>>(esub, epred, eobj, B1, B2, EX, SEG);

    proj_kernel<false><<<pg, 256, 0, stream>>>(x, tv, nullptr, B2, nullptr);  // V -> B2
    hipMemsetAsync(B1, 0, (size_t)N_REL * N_NODES * EMBD * sizeof(float), stream);  // AGG = 0

    edge_agg_kernel<<<((size_t)N_EDGE * EMBD) / 256, 256, 0, stream>>>(esub, epred, eobj, B2, EX, SEG, B1);

    unify_kernel<<<(N_NODES + 31) / 32, 256, 0, stream>>>(B1, UT, out);
}

// Round 4
// 537.257 us; speedup vs baseline: 2.2768x; 2.2768x over previous
//
#include <hip/hip_runtime.h>

constexpr int N_NODES = 50000;
constexpr int N_REL   = 4;
constexpr int EMBD    = 128;
constexpr int N_HEAD  = 4;
constexpr int HS      = 32;
constexpr int N_EDGE  = 400000;

// ---------------------------------------------------------------------------
// K/Q/V projection (per-head 32x32 block-diagonal). KNOWN GOOD (round 2).
// P[r][n][j] = sum_k W[r][h(j)][s(j)][k] * x[n][h*32+k],  j = h*32+s
// ---------------------------------------------------------------------------
template<bool DUAL>
__global__ __launch_bounds__(256) void proj_kernel(
    const float* __restrict__ x,
    const float* __restrict__ W1,
    const float* __restrict__ W2,
    float* __restrict__ P1, float* __restrict__ P2)
{
    const int r    = blockIdx.y;
    const int n0   = blockIdx.x * 64;
    const int t    = threadIdx.x;
    const int j    = t & 127;
    const int half = t >> 7;
    const int h    = j >> 5;
    const int s    = j & 31;

    __shared__ float xs[64 * 128];
    {
        const float4* x4 = (const float4*)(x + (size_t)n0 * 128);
        float4* xs4 = (float4*)xs;
        for (int idx = t; idx < 64 * 32; idx += 256) {
            int n = n0 + (idx >> 5);
            float4 v = make_float4(0.f, 0.f, 0.f, 0.f);
            if (n < N_NODES) v = x4[idx];
            xs4[idx] = v;
        }
    }

    float w1[32], w2[32];
    {
        const float* w1p = W1 + (((r * N_HEAD + h) * HS + s) * HS);
        #pragma unroll
        for (int k = 0; k < 32; k++) w1[k] = w1p[k];
        if (DUAL) {
            const float* w2p = W2 + (((r * N_HEAD + h) * HS + s) * HS);
            #pragma unroll
            for (int k = 0; k < 32; k++) w2[k] = w2p[k];
        }
    }
    __syncthreads();

    #pragma unroll 1
    for (int i = 0; i < 32; i++) {
        int n = n0 + half * 32 + i;
        if (n >= N_NODES) break;               // uniform within wave
        const float* xp = &xs[(half * 32 + i) * 128 + h * 32];
        float a1 = 0.f, a2 = 0.f;
        #pragma unroll
        for (int k = 0; k < 32; k++) {
            float xv = xp[k];
            a1 += w1[k] * xv;
            if (DUAL) a2 += w2[k] * xv;
        }
        size_t o = ((size_t)r * N_NODES + n) * 128 + j;
        P1[o] = a1;
        if (DUAL) P2[o] = a2;
    }
}

// ---------------------------------------------------------------------------
// UT[r][j][i] = unify[r][i][j]. KNOWN GOOD (round 2). 256 KB fp32, L2-hot.
// ---------------------------------------------------------------------------
__global__ __launch_bounds__(256) void transpose_u(
    const float* __restrict__ U, float* __restrict__ UT)
{
    int idx = blockIdx.x * 256 + threadIdx.x;          // r*16384 + i*128 + j
    int r = idx >> 14, rem = idx & 16383, i = rem >> 7, jj = rem & 127;
    UT[(r * 128 + jj) * 128 + i] = U[idx];
}

// ---------------------------------------------------------------------------
// One thread per (edge, head). KNOWN GOOD (round 2). exp without max-sub
// (dot bounded ~±10, fp32-exp safe; softmax analytically identical).
// ---------------------------------------------------------------------------
__global__ __launch_bounds__(256) void edge_dot_kernel(
    const int* __restrict__ esub, const int* __restrict__ epred, const int* __restrict__ eobj,
    const float* __restrict__ K, const float* __restrict__ Q,
    float* __restrict__ EX, float* __restrict__ SEG)
{
    int gid = blockIdx.x * 256 + threadIdx.x;          // exact: 6250*256 == E*H
    int e = gid >> 2, h = gid & 3;
    int pred = epred[e], sub = esub[e], obj = eobj[e];
    const float4* kp = (const float4*)(K + ((size_t)pred * N_NODES + sub) * 128 + h * 32);
    const float4* qp = (const float4*)(Q + ((size_t)pred * N_NODES + obj) * 128 + h * 32);
    float dot = 0.f;
    #pragma unroll
    for (int k = 0; k < 8; k++) {
        float4 a = kp[k], b = qp[k];
        dot += a.x * b.x + a.y * b.y + a.z * b.z + a.w * b.w;
    }
    float ex = __expf(dot);
    EX[gid] = ex;
    atomicAdd(&SEG[(pred * N_NODES + sub) * 4 + h], ex);
}

// ---------------------------------------------------------------------------
// 128 threads per edge: AGG[row][idx] += ex * V[pred,obj,idx]  (UNNORMALIZED;
// division by SEG moved into unify_tiled — algebraically identical since the
// per-(row,h) denominator distributes over the segment sum).
// ---------------------------------------------------------------------------
__global__ __launch_bounds__(256) void edge_agg_kernel(
    const int* __restrict__ esub, const int* __restrict__ epred, const int* __restrict__ eobj,
    const float* __restrict__ V, const float* __restrict__ EX,
    float* __restrict__ AGG)
{
    long long gid = (long long)blockIdx.x * 256 + threadIdx.x;  // exact: 200000*256 == E*128
    int e   = (int)(gid >> 7);
    int idx = (int)(gid & 127);
    int h   = idx >> 5;
    int pred = epred[e], sub = esub[e], obj = eobj[e];
    int row = pred * N_NODES + sub;
    float ex = EX[e * 4 + h];
    float v = V[((size_t)pred * N_NODES + obj) * 128 + idx];
    atomicAdd(&AGG[(size_t)row * 128 + idx], ex * v);
}

// ---------------------------------------------------------------------------
// out[n][i] = relu( sum_r sum_j UT[r][j][i] * AGG[r][n][j] / SEG[r][n][h(j)] )
// LDS-tiled register-blocked GEMM replacing round-2's cache-thrashing unify
// (which re-read 32KB of UT per thread through L1: 825us, VALUBusy 6%).
// Block: 64 nodes x 128 i. Thread (tn=t>>4, ti=t&15): 4 nodes x 8 i, acc[4][8].
// as: AGG tile [64][132] (normalized on load); us: UT chunk [32][132].
// Padding 132 kills power-of-2 bank strides. Fuses r-sum + relu (no extra pass).
// ---------------------------------------------------------------------------
__global__ __launch_bounds__(256) void unify_tiled(
    const float* __restrict__ AGG, const float* __restrict__ SEG,
    const float* __restrict__ UT, float* __restrict__ out)
{
    const int t  = threadIdx.x;
    const int n0 = blockIdx.x * 64;
    const int tn = t >> 4;          // 0..15 -> nodes tn*4 .. +3
    const int ti = t & 15;          // 0..15 -> i0 = ti*8

    __shared__ float as[64 * 132];
    __shared__ float us[32 * 132];

    float acc[4][8];
    #pragma unroll
    for (int q = 0; q < 4; q++)
        #pragma unroll
        for (int w = 0; w < 8; w++) acc[q][w] = 0.f;

    for (int r = 0; r < N_REL; r++) {
        __syncthreads();   // previous r's readers of as/us are done
        {   // stage AGG[r][n0..n0+63][0..127] -> as, normalizing by SEG
            const float4* a4 = (const float4*)(AGG + ((size_t)r * N_NODES + n0) * 128);
            for (int idx = t; idx < 64 * 32; idx += 256) {
                int n = idx >> 5, c4 = idx & 31;
                float4 v = make_float4(0.f, 0.f, 0.f, 0.f);
                if (n0 + n < N_NODES) {
                    v = a4[idx];
                    float segv = SEG[((size_t)r * N_NODES + n0 + n) * 4 + (c4 >> 3)];
                    float inv = (segv > 0.f) ? 1.0f / segv : 0.f;   // empty rows: 0, not NaN
                    v.x *= inv; v.y *= inv; v.z *= inv; v.w *= inv;
                }
                *(float4*)&as[n * 132 + c4 * 4] = v;
            }
        }
        for (int kc = 0; kc < 4; kc++) {
            if (kc) __syncthreads();          // protect us before restage
            {   // stage UT[r][kc*32 .. +31][0..127] -> us
                const float4* u4 = (const float4*)(UT + ((size_t)r * 128 + kc * 32) * 128);
                #pragma unroll
                for (int w = 0; w < 4; w++) {
                    int pos = w * 256 + t;       // 1024 float4 slots
                    int kk = pos >> 5, i4 = pos & 31;
                    *(float4*)&us[kk * 132 + i4 * 4] = u4[pos];
                }
            }
            __syncthreads();

            const int k0 = kc * 32;
            #pragma unroll 4
            for (int kk = 0; kk < 32; kk++) {
                float b[8];
                *(float4*)&b[0] = *(const float4*)&us[kk * 132 + ti * 8];
                *(float4*)&b[4] = *(const float4*)&us[kk * 132 + ti * 8 + 4];
                #pragma unroll
                for (int q = 0; q < 4; q++) {
                    float a = as[(tn * 4 + q) * 132 + k0 + kk];
                    #pragma unroll
                    for (int w = 0; w < 8; w++) acc[q][w] += a * b[w];
                }
            }
        }
    }

    #pragma unroll
    for (int q = 0; q < 4; q++) {
        int n = n0 + tn * 4 + q;
        if (n < N_NODES) {
            float* op = out + (size_t)n * 128 + ti * 8;
            *(float4*)op = make_float4(fmaxf(acc[q][0], 0.f), fmaxf(acc[q][1], 0.f),
                                       fmaxf(acc[q][2], 0.f), fmaxf(acc[q][3], 0.f));
            *(float4*)(op + 4) = make_float4(fmaxf(acc[q][4], 0.f), fmaxf(acc[q][5], 0.f),
                                             fmaxf(acc[q][6], 0.f), fmaxf(acc[q][7], 0.f));
        }
    }
}

extern "C" void kernel_launch(void* const* d_in, const int* in_sizes, int n_in,
                              void* d_out, int out_size, void* d_ws, size_t ws_size,
                              hipStream_t stream)
{
    const float* x  = (const float*)d_in[0];
    const float* tk = (const float*)d_in[1];
    const float* tq = (const float*)d_in[2];
    const float* tv = (const float*)d_in[3];
    const float* un = (const float*)d_in[4];
    const int* esub  = (const int*)d_in[5];
    const int* epred = (const int*)d_in[6];
    const int* eobj  = (const int*)d_in[7];
    float* out = (float*)d_out;

    // Workspace layout (bytes), total ~214.7 MB (identical to round 2):
    //   B1: [R][N][128] fp32  (K, then zeroed -> AGG unnorm) @ 0          (102,400,000)
    //   B2: [R][N][128] fp32  (Q, then overwritten by V)     @ 102400000  (102,400,000)
    //   EX: [E][H]      fp32  (unnormalized exp(dot))        @ 204800000  (  6,400,000)
    //   SEG:[R*N][H]    fp32  (softmax denominators)         @ 211200000  (  3,200,000)
    //   UT: [R][128][128] fp32 (unify transposed)            @ 214400000  (    262,144)
    char* ws = (char*)d_ws;
    float* B1  = (float*)(ws);
    float* B2  = (float*)(ws + 102400000);
    float* EX  = (float*)(ws + 204800000);
    float* SEG = (float*)(ws + 211200000);
    float* UT  = (float*)(ws + 214400000);

    transpose_u<<<(N_REL * EMBD * EMBD) / 256, 256, 0, stream>>>(un, UT);
    hipMemsetAsync(SEG, 0, (size_t)N_REL * N_NODES * N_HEAD * sizeof(float), stream);

    dim3 pg((N_NODES + 63) / 64, N_REL);
    proj_kernel<true><<<pg, 256, 0, stream>>>(x, tk, tq, B1, B2);   // K -> B1, Q -> B2

    edge_dot_kernel<<<(N_EDGE * N_HEAD) / 256, 256, 0, stream>>>(esub, epred, eobj, B1, B2, EX, SEG);

    proj_kernel<false><<<pg, 256, 0, stream>>>(x, tv, nullptr, B2, nullptr);  // V -> B2 (Q dead)
    hipMemsetAsync(B1, 0, (size_t)N_REL * N_NODES * EMBD * sizeof(float), stream);  // AGG = 0 (K dead)

    edge_agg_kernel<<<(int)(((size_t)N_EDGE * EMBD) / 256), 256, 0, stream>>>(esub, epred, eobj, B2, EX, B1);

    unify_tiled<<<(N_NODES + 63) / 64, 256, 0, stream>>>(B1, SEG, UT, out);
}

// Round 5
// 487.578 us; speedup vs baseline: 2.5088x; 1.1019x over previous
//
#include <hip/hip_runtime.h>

constexpr int N_NODES = 50000;
constexpr int N_REL   = 4;
constexpr int EMBD    = 128;
constexpr int N_HEAD  = 4;
constexpr int HS      = 32;
constexpr int N_EDGE  = 400000;

typedef __attribute__((ext_vector_type(8))) short bf16x8;
typedef __attribute__((ext_vector_type(4))) float f32x4;

__device__ __forceinline__ unsigned short f2b(float f) {
    unsigned int u = __float_as_uint(f);
    u += 0x7FFF + ((u >> 16) & 1);   // round-to-nearest-even
    return (unsigned short)(u >> 16);
}

// ---------------------------------------------------------------------------
// K/Q/V projection (per-head 32x32 block-diagonal). KNOWN GOOD (round 2/4).
// P[r][n][j] = sum_k W[r][h(j)][s(j)][k] * x[n][h*32+k],  j = h*32+s
// ---------------------------------------------------------------------------
template<bool DUAL>
__global__ __launch_bounds__(256) void proj_kernel(
    const float* __restrict__ x,
    const float* __restrict__ W1,
    const float* __restrict__ W2,
    float* __restrict__ P1, float* __restrict__ P2)
{
    const int r    = blockIdx.y;
    const int n0   = blockIdx.x * 64;
    const int t    = threadIdx.x;
    const int j    = t & 127;
    const int half = t >> 7;
    const int h    = j >> 5;
    const int s    = j & 31;

    __shared__ float xs[64 * 128];
    {
        const float4* x4 = (const float4*)(x + (size_t)n0 * 128);
        float4* xs4 = (float4*)xs;
        for (int idx = t; idx < 64 * 32; idx += 256) {
            int n = n0 + (idx >> 5);
            float4 v = make_float4(0.f, 0.f, 0.f, 0.f);
            if (n < N_NODES) v = x4[idx];
            xs4[idx] = v;
        }
    }

    float w1[32], w2[32];
    {
        const float* w1p = W1 + (((r * N_HEAD + h) * HS + s) * HS);
        #pragma unroll
        for (int k = 0; k < 32; k++) w1[k] = w1p[k];
        if (DUAL) {
            const float* w2p = W2 + (((r * N_HEAD + h) * HS + s) * HS);
            #pragma unroll
            for (int k = 0; k < 32; k++) w2[k] = w2p[k];
        }
    }
    __syncthreads();

    #pragma unroll 1
    for (int i = 0; i < 32; i++) {
        int n = n0 + half * 32 + i;
        if (n >= N_NODES) break;               // uniform within wave
        const float* xp = &xs[(half * 32 + i) * 128 + h * 32];
        float a1 = 0.f, a2 = 0.f;
        #pragma unroll
        for (int k = 0; k < 32; k++) {
            float xv = xp[k];
            a1 += w1[k] * xv;
            if (DUAL) a2 += w2[k] * xv;
        }
        size_t o = ((size_t)r * N_NODES + n) * 128 + j;
        P1[o] = a1;
        if (DUAL) P2[o] = a2;
    }
}

// ---------------------------------------------------------------------------
// Ub[r][i][j] = bf16(unify[r][i][j]) — plain dtype-cast copy (the MFMA B
// operand wants exactly the natural [i][j] layout with j contiguous). 128 KB.
// ---------------------------------------------------------------------------
__global__ __launch_bounds__(256) void cast_u(
    const float* __restrict__ U, unsigned short* __restrict__ Ub)
{
    int idx = blockIdx.x * 256 + threadIdx.x;      // 256 blocks * 256 = 65536 exact
    Ub[idx] = f2b(U[idx]);
}

// ---------------------------------------------------------------------------
// One thread per (edge, head). KNOWN GOOD (round 2/4). exp without max-sub
// (dot bounded ~±10, fp32-exp safe; softmax analytically identical).
// ---------------------------------------------------------------------------
__global__ __launch_bounds__(256) void edge_dot_kernel(
    const int* __restrict__ esub, const int* __restrict__ epred, const int* __restrict__ eobj,
    const float* __restrict__ K, const float* __restrict__ Q,
    float* __restrict__ EX, float* __restrict__ SEG)
{
    int gid = blockIdx.x * 256 + threadIdx.x;          // exact: 6250*256 == E*H
    int e = gid >> 2, h = gid & 3;
    int pred = epred[e], sub = esub[e], obj = eobj[e];
    const float4* kp = (const float4*)(K + ((size_t)pred * N_NODES + sub) * 128 + h * 32);
    const float4* qp = (const float4*)(Q + ((size_t)pred * N_NODES + obj) * 128 + h * 32);
    float dot = 0.f;
    #pragma unroll
    for (int k = 0; k < 8; k++) {
        float4 a = kp[k], b = qp[k];
        dot += a.x * b.x + a.y * b.y + a.z * b.z + a.w * b.w;
    }
    float ex = __expf(dot);
    EX[gid] = ex;
    atomicAdd(&SEG[(pred * N_NODES + sub) * 4 + h], ex);
}

// ---------------------------------------------------------------------------
// 128 threads per edge: AGG[row][idx] += ex * V[pred,obj,idx]  (UNNORMALIZED;
// division by SEG lives in unify_mfma's A-staging). KNOWN GOOD (round 4).
// ---------------------------------------------------------------------------
__global__ __launch_bounds__(256) void edge_agg_kernel(
    const int* __restrict__ esub, const int* __restrict__ epred, const int* __restrict__ eobj,
    const float* __restrict__ V, const float* __restrict__ EX,
    float* __restrict__ AGG)
{
    long long gid = (long long)blockIdx.x * 256 + threadIdx.x;  // exact: 200000*256 == E*128
    int e   = (int)(gid >> 7);
    int idx = (int)(gid & 127);
    int h   = idx >> 5;
    int pred = epred[e], sub = esub[e], obj = eobj[e];
    int row = pred * N_NODES + sub;
    float ex = EX[e * 4 + h];
    float v = V[((size_t)pred * N_NODES + obj) * 128 + idx];
    atomicAdd(&AGG[(size_t)row * 128 + idx], ex * v);
}

// ---------------------------------------------------------------------------
// out[n][i] = relu( sum_r sum_j U[r][i][j] * AGG[r][n][j] / SEG[r][n][h(j)] )
// bf16-MFMA replacement for the fp32 vector GEMM (which was at its 157 TF
// structural roofline ~167us). A = normalized AGG tile cast to bf16 in LDS;
// B = Ub (bf16 unify, natural layout). fp32 MFMA accumulation.
// Block: 64 nodes x 128 i, 4 waves; wave w owns node-rows [16w,16w+16) x all i.
// Fragment maps (m89-verified): A row=lane&15, k=8*(lane>>4)+j (contiguous);
// B col=lane&15, same k; D col=lane&15, row=4*(lane>>4)+reg.
// LDS rows padded to 136 elems (272B): frag reads are 2-way bank alias (free).
// ---------------------------------------------------------------------------
__global__ __launch_bounds__(256) void unify_mfma(
    const float* __restrict__ AGG, const float* __restrict__ SEG,
    const unsigned short* __restrict__ Ub, float* __restrict__ out)
{
    __shared__ unsigned short As[64 * 136];    // A tile: [node][k] bf16
    __shared__ unsigned short Bs[128 * 136];   // B tile: [i][k] bf16

    const int t    = threadIdx.x;
    const int lane = t & 63;
    const int w    = t >> 6;
    const int n0   = blockIdx.x * 64;

    f32x4 acc[8];
    #pragma unroll
    for (int f = 0; f < 8; f++) acc[f] = (f32x4){0.f, 0.f, 0.f, 0.f};

    for (int r = 0; r < N_REL; r++) {
        __syncthreads();   // previous r's fragment readers done before restage

        {   // stage A: AGG[r][n0..n0+63][0..127] -> normalize -> bf16
            const float4* a4 = (const float4*)(AGG + ((size_t)r * N_NODES + n0) * 128);
            for (int idx = t; idx < 64 * 32; idx += 256) {
                int nn = idx >> 5, c4 = idx & 31;          // k = c4*4, h = c4>>3
                float4 v = make_float4(0.f, 0.f, 0.f, 0.f);
                if (n0 + nn < N_NODES) {
                    v = a4[idx];
                    float segv = SEG[((size_t)r * N_NODES + n0 + nn) * 4 + (c4 >> 3)];
                    float inv = (segv > 0.f) ? 1.0f / segv : 0.f;   // empty rows: 0, not NaN
                    v.x *= inv; v.y *= inv; v.z *= inv; v.w *= inv;
                }
                ushort4 b = make_ushort4(f2b(v.x), f2b(v.y), f2b(v.z), f2b(v.w));
                *(ushort4*)&As[nn * 136 + c4 * 4] = b;
            }
        }
        {   // stage B: Ub[r][0..127][0..127] straight copy (L2-hot, shared by all blocks)
            const ushort4* u4 = (const ushort4*)(Ub + (size_t)r * 128 * 128);
            for (int idx = t; idx < 128 * 32; idx += 256) {
                int i = idx >> 5, c4 = idx & 31;
                *(ushort4*)&Bs[i * 136 + c4 * 4] = u4[idx];
            }
        }
        __syncthreads();

        const int row = lane & 15;     // A row / B col
        const int kg  = lane >> 4;     // k-group
        #pragma unroll
        for (int ks = 0; ks < 4; ks++) {
            const int kofs = ks * 32 + kg * 8;
            bf16x8 a = *(const bf16x8*)&As[(w * 16 + row) * 136 + kofs];
            #pragma unroll
            for (int f = 0; f < 8; f++) {
                bf16x8 b = *(const bf16x8*)&Bs[(f * 16 + row) * 136 + kofs];
                acc[f] = __builtin_amdgcn_mfma_f32_16x16x32_bf16(a, b, acc[f], 0, 0, 0);
            }
        }
    }

    // epilogue: D col=lane&15, row=4*(lane>>4)+reg; relu + fp32 store
    const int col  = lane & 15;
    const int rgrp = lane >> 4;
    #pragma unroll
    for (int f = 0; f < 8; f++) {
        #pragma unroll
        for (int reg = 0; reg < 4; reg++) {
            int n = n0 + w * 16 + rgrp * 4 + reg;
            if (n < N_NODES)
                out[(size_t)n * 128 + f * 16 + col] = fmaxf(acc[f][reg], 0.f);
        }
    }
}

extern "C" void kernel_launch(void* const* d_in, const int* in_sizes, int n_in,
                              void* d_out, int out_size, void* d_ws, size_t ws_size,
                              hipStream_t stream)
{
    const float* x  = (const float*)d_in[0];
    const float* tk = (const float*)d_in[1];
    const float* tq = (const float*)d_in[2];
    const float* tv = (const float*)d_in[3];
    const float* un = (const float*)d_in[4];
    const int* esub  = (const int*)d_in[5];
    const int* epred = (const int*)d_in[6];
    const int* eobj  = (const int*)d_in[7];
    float* out = (float*)d_out;

    // Workspace layout (bytes), total ~214.6 MB:
    //   B1: [R][N][128] fp32  (K, then zeroed -> AGG unnorm) @ 0          (102,400,000)
    //   B2: [R][N][128] fp32  (Q, then overwritten by V)     @ 102400000  (102,400,000)
    //   EX: [E][H]      fp32  (unnormalized exp(dot))        @ 204800000  (  6,400,000)
    //   SEG:[R*N][H]    fp32  (softmax denominators)         @ 211200000  (  3,200,000)
    //   Ub: [R][128][128] bf16 (unify cast, natural layout)  @ 214400000  (    131,072)
    char* ws = (char*)d_ws;
    float* B1  = (float*)(ws);
    float* B2  = (float*)(ws + 102400000);
    float* EX  = (float*)(ws + 204800000);
    float* SEG = (float*)(ws + 211200000);
    unsigned short* Ub = (unsigned short*)(ws + 214400000);

    cast_u<<<(N_REL * EMBD * EMBD) / 256, 256, 0, stream>>>(un, Ub);
    hipMemsetAsync(SEG, 0, (size_t)N_REL * N_NODES * N_HEAD * sizeof(float), stream);

    dim3 pg((N_NODES + 63) / 64, N_REL);
    proj_kernel<true><<<pg, 256, 0, stream>>>(x, tk, tq, B1, B2);   // K -> B1, Q -> B2

    edge_dot_kernel<<<(N_EDGE * N_HEAD) / 256, 256, 0, stream>>>(esub, epred, eobj, B1, B2, EX, SEG);

    proj_kernel<false><<<pg, 256, 0, stream>>>(x, tv, nullptr, B2, nullptr);  // V -> B2 (Q dead)
    hipMemsetAsync(B1, 0, (size_t)N_REL * N_NODES * EMBD * sizeof(float), stream);  // AGG = 0 (K dead)

    edge_agg_kernel<<<(int)(((size_t)N_EDGE * EMBD) / 256), 256, 0, stream>>>(esub, epred, eobj, B2, EX, B1);

    unify_mfma<<<(N_NODES + 63) / 64, 256, 0, stream>>>(B1, SEG, Ub, out);
}

// Round 6
// 434.854 us; speedup vs baseline: 2.8130x; 1.1212x over previous
//
#include <hip/hip_runtime.h>

constexpr int N_NODES = 50000;
constexpr int N_REL   = 4;
constexpr int EMBD    = 128;
constexpr int N_HEAD  = 4;
constexpr int HS      = 32;
constexpr int N_EDGE  = 400000;
constexpr int N_ROWS  = N_REL * N_NODES;        // 200000 segment rows

typedef __attribute__((ext_vector_type(8))) short bf16x8;
typedef __attribute__((ext_vector_type(4))) float f32x4;

__device__ __forceinline__ unsigned short f2b(float f) {
    unsigned int u = __float_as_uint(f);
    u += 0x7FFF + ((u >> 16) & 1);   // round-to-nearest-even
    return (unsigned short)(u >> 16);
}

// ---------------------------------------------------------------------------
// K/Q/V projection (per-head 32x32 block-diagonal). KNOWN GOOD (rounds 2-5).
// ---------------------------------------------------------------------------
template<bool DUAL>
__global__ __launch_bounds__(256) void proj_kernel(
    const float* __restrict__ x,
    const float* __restrict__ W1,
    const float* __restrict__ W2,
    float* __restrict__ P1, float* __restrict__ P2)
{
    const int r    = blockIdx.y;
    const int n0   = blockIdx.x * 64;
    const int t    = threadIdx.x;
    const int j    = t & 127;
    const int half = t >> 7;
    const int h    = j >> 5;
    const int s    = j & 31;

    __shared__ float xs[64 * 128];
    {
        const float4* x4 = (const float4*)(x + (size_t)n0 * 128);
        float4* xs4 = (float4*)xs;
        for (int idx = t; idx < 64 * 32; idx += 256) {
            int n = n0 + (idx >> 5);
            float4 v = make_float4(0.f, 0.f, 0.f, 0.f);
            if (n < N_NODES) v = x4[idx];
            xs4[idx] = v;
        }
    }

    float w1[32], w2[32];
    {
        const float* w1p = W1 + (((r * N_HEAD + h) * HS + s) * HS);
        #pragma unroll
        for (int k = 0; k < 32; k++) w1[k] = w1p[k];
        if (DUAL) {
            const float* w2p = W2 + (((r * N_HEAD + h) * HS + s) * HS);
            #pragma unroll
            for (int k = 0; k < 32; k++) w2[k] = w2p[k];
        }
    }
    __syncthreads();

    #pragma unroll 1
    for (int i = 0; i < 32; i++) {
        int n = n0 + half * 32 + i;
        if (n >= N_NODES) break;               // uniform within wave
        const float* xp = &xs[(half * 32 + i) * 128 + h * 32];
        float a1 = 0.f, a2 = 0.f;
        #pragma unroll
        for (int k = 0; k < 32; k++) {
            float xv = xp[k];
            a1 += w1[k] * xv;
            if (DUAL) a2 += w2[k] * xv;
        }
        size_t o = ((size_t)r * N_NODES + n) * 128 + j;
        P1[o] = a1;
        if (DUAL) P2[o] = a2;
    }
}

// ---------------------------------------------------------------------------
// Ub[r][i][j] = bf16(unify[r][i][j]). KNOWN GOOD (round 5). 128 KB, L2-hot.
// ---------------------------------------------------------------------------
__global__ __launch_bounds__(256) void cast_u(
    const float* __restrict__ U, unsigned short* __restrict__ Ub)
{
    int idx = blockIdx.x * 256 + threadIdx.x;      // 256*256 = 65536 exact
    Ub[idx] = f2b(U[idx]);
}

// ---------------------------------------------------------------------------
// One thread per (edge, head): EX = exp(dot). No SEG atomics anymore —
// denominators are now summed deterministically per row in agg_csr.
// ---------------------------------------------------------------------------
__global__ __launch_bounds__(256) void edge_dot_kernel(
    const int* __restrict__ esub, const int* __restrict__ epred, const int* __restrict__ eobj,
    const float* __restrict__ K, const float* __restrict__ Q,
    float* __restrict__ EX)
{
    int gid = blockIdx.x * 256 + threadIdx.x;          // exact: 6250*256 == E*H
    int e = gid >> 2, h = gid & 3;
    int pred = epred[e], sub = esub[e], obj = eobj[e];
    const float4* kp = (const float4*)(K + ((size_t)pred * N_NODES + sub) * 128 + h * 32);
    const float4* qp = (const float4*)(Q + ((size_t)pred * N_NODES + obj) * 128 + h * 32);
    float dot = 0.f;
    #pragma unroll
    for (int k = 0; k < 8; k++) {
        float4 a = kp[k], b = qp[k];
        dot += a.x * b.x + a.y * b.y + a.z * b.z + a.w * b.w;
    }
    EX[gid] = __expf(dot);
}

// ---------------------------------------------------------------------------
// CSR build: histogram -> 3-phase deterministic exclusive scan -> scatter.
// 200000 rows = 196 blocks x 1024 elems.
// ---------------------------------------------------------------------------
__global__ __launch_bounds__(256) void hist_kernel(
    const int* __restrict__ esub, const int* __restrict__ epred, int* __restrict__ HIST)
{
    int e = blockIdx.x * 256 + threadIdx.x;
    if (e < N_EDGE) atomicAdd(&HIST[epred[e] * N_NODES + esub[e]], 1);
}

__global__ __launch_bounds__(256) void scan_p1(      // per-block totals
    const int* __restrict__ HIST, int* __restrict__ SUMS)
{
    int b = blockIdx.x, t = threadIdx.x;
    int base = b * 1024 + t * 4;
    int s = 0;
    #pragma unroll
    for (int k = 0; k < 4; k++) if (base + k < N_ROWS) s += HIST[base + k];
    __shared__ int red[256];
    red[t] = s; __syncthreads();
    for (int st = 128; st > 0; st >>= 1) {
        if (t < st) red[t] += red[t + st];
        __syncthreads();
    }
    if (t == 0) SUMS[b] = red[0];
}

__global__ __launch_bounds__(256) void scan_p2(      // scan the 196 totals
    const int* __restrict__ SUMS, int* __restrict__ SOFF, int* __restrict__ OFFS)
{
    int t = threadIdx.x;
    __shared__ int sh[256];
    int o = (t < 196) ? SUMS[t] : 0;
    sh[t] = o; __syncthreads();
    for (int st = 1; st < 256; st <<= 1) {
        int v = (t >= st) ? sh[t - st] : 0;
        __syncthreads();
        sh[t] += v;
        __syncthreads();
    }
    if (t < 196) SOFF[t] = sh[t] - o;                // exclusive
    if (t == 0)  OFFS[N_ROWS] = sh[255];             // total == N_EDGE
}

__global__ __launch_bounds__(256) void scan_p3(      // full exclusive scan
    const int* __restrict__ HIST, const int* __restrict__ SOFF, int* __restrict__ OFFS)
{
    int b = blockIdx.x, t = threadIdx.x;
    int base = b * 1024 + t * 4;
    int v[4], tot = 0;
    #pragma unroll
    for (int k = 0; k < 4; k++) {
        v[k] = (base + k < N_ROWS) ? HIST[base + k] : 0;
        tot += v[k];
    }
    __shared__ int sh[256];
    sh[t] = tot; __syncthreads();
    for (int st = 1; st < 256; st <<= 1) {
        int q = (t >= st) ? sh[t - st] : 0;
        __syncthreads();
        sh[t] += q;
        __syncthreads();
    }
    int run = SOFF[b] + (sh[t] - tot);
    #pragma unroll
    for (int k = 0; k < 4; k++) {
        if (base + k < N_ROWS) { OFFS[base + k] = run; run += v[k]; }
    }
}

__global__ __launch_bounds__(256) void cursor_copy(
    const int* __restrict__ OFFS, int* __restrict__ CURSOR)
{
    int i = blockIdx.x * 256 + threadIdx.x;
    if (i < N_ROWS) CURSOR[i] = OFFS[i];
}

__global__ __launch_bounds__(256) void scatter_kernel(
    const int* __restrict__ esub, const int* __restrict__ epred,
    int* __restrict__ CURSOR, int* __restrict__ EIDS)
{
    int e = blockIdx.x * 256 + threadIdx.x;
    if (e < N_EDGE) {
        int row = epred[e] * N_NODES + esub[e];
        int pos = atomicAdd(&CURSOR[row], 1);
        EIDS[pos] = e;
    }
}

// ---------------------------------------------------------------------------
// One WAVE per row: AGG[row][j] = (sum_{e in row} EX[e][h(j)] * V[pred,obj_e][j])
//                               / (sum_{e in row} EX[e][h(j)])
// Lane owns j=lane and j+64. V row reads are two coalesced 256B transactions;
// EX reads are lane-broadcast. Seg-denominator summed IN REGISTERS (deterministic,
// replaces 1.6M SEG atomics + SEG buffer). Writes every row exactly once —
// zero fp atomics, and empty rows write zeros (replaces 102.4MB memset).
// ---------------------------------------------------------------------------
__global__ __launch_bounds__(256) void agg_csr(
    const int* __restrict__ eobj, const int* __restrict__ OFFS, const int* __restrict__ EIDS,
    const float* __restrict__ V, const float* __restrict__ EX,
    float* __restrict__ AGG)
{
    const int t    = threadIdx.x;
    const int lane = t & 63;
    const int row  = blockIdx.x * 4 + (t >> 6);     // exact: 50000*4 == N_ROWS
    const int pred = row / N_NODES;                 // wave-uniform
    const int hA   = lane >> 5;                     // head of j=lane   (0/1)
    // head of j=lane+64 is hA+2

    const int beg = OFFS[row], end = OFFS[row + 1];

    float accA = 0.f, accB = 0.f, segA = 0.f, segB = 0.f;
    for (int i = beg; i < end; i++) {
        int e   = EIDS[i];
        int obj = eobj[e];
        float exA = EX[e * 4 + hA];
        float exB = EX[e * 4 + 2 + hA];
        const float* vp = V + ((size_t)pred * N_NODES + obj) * 128;
        accA += exA * vp[lane];
        accB += exB * vp[lane + 64];
        segA += exA;
        segB += exB;
    }
    float invA = (segA > 0.f) ? 1.0f / segA : 0.f;   // empty row -> 0, not NaN
    float invB = (segB > 0.f) ? 1.0f / segB : 0.f;
    float* op = AGG + (size_t)row * 128;
    op[lane]      = accA * invA;
    op[lane + 64] = accB * invB;
}

// ---------------------------------------------------------------------------
// out[n][i] = relu( sum_r sum_j U[r][i][j] * AGGnorm[r][n][j] )  — bf16 MFMA,
// fp32 accum. KNOWN GOOD (round 5); A-staging simplified (AGG pre-normalized).
// ---------------------------------------------------------------------------
__global__ __launch_bounds__(256) void unify_mfma(
    const float* __restrict__ AGG,
    const unsigned short* __restrict__ Ub, float* __restrict__ out)
{
    __shared__ unsigned short As[64 * 136];    // A tile: [node][k] bf16
    __shared__ unsigned short Bs[128 * 136];   // B tile: [i][k] bf16

    const int t    = threadIdx.x;
    const int lane = t & 63;
    const int w    = t >> 6;
    const int n0   = blockIdx.x * 64;

    f32x4 acc[8];
    #pragma unroll
    for (int f = 0; f < 8; f++) acc[f] = (f32x4){0.f, 0.f, 0.f, 0.f};

    for (int r = 0; r < N_REL; r++) {
        __syncthreads();

        {   // stage A: AGG[r][n0..n0+63][0..127] -> bf16
            const float4* a4 = (const float4*)(AGG + ((size_t)r * N_NODES + n0) * 128);
            for (int idx = t; idx < 64 * 32; idx += 256) {
                int nn = idx >> 5, c4 = idx & 31;
                float4 v = make_float4(0.f, 0.f, 0.f, 0.f);
                if (n0 + nn < N_NODES) v = a4[idx];
                ushort4 b = make_ushort4(f2b(v.x), f2b(v.y), f2b(v.z), f2b(v.w));
                *(ushort4*)&As[nn * 136 + c4 * 4] = b;
            }
        }
        {   // stage B: Ub[r] straight copy (L2-hot)
            const ushort4* u4 = (const ushort4*)(Ub + (size_t)r * 128 * 128);
            for (int idx = t; idx < 128 * 32; idx += 256) {
                int i = idx >> 5, c4 = idx & 31;
                *(ushort4*)&Bs[i * 136 + c4 * 4] = u4[idx];
            }
        }
        __syncthreads();

        const int row = lane & 15;     // A row / B col
        const int kg  = lane >> 4;     // k-group
        #pragma unroll
        for (int ks = 0; ks < 4; ks++) {
            const int kofs = ks * 32 + kg * 8;
            bf16x8 a = *(const bf16x8*)&As[(w * 16 + row) * 136 + kofs];
            #pragma unroll
            for (int f = 0; f < 8; f++) {
                bf16x8 b = *(const bf16x8*)&Bs[(f * 16 + row) * 136 + kofs];
                acc[f] = __builtin_amdgcn_mfma_f32_16x16x32_bf16(a, b, acc[f], 0, 0, 0);
            }
        }
    }

    const int col  = lane & 15;
    const int rgrp = lane >> 4;
    #pragma unroll
    for (int f = 0; f < 8; f++) {
        #pragma unroll
        for (int reg = 0; reg < 4; reg++) {
            int n = n0 + w * 16 + rgrp * 4 + reg;
            if (n < N_NODES)
                out[(size_t)n * 128 + f * 16 + col] = fmaxf(acc[f][reg], 0.f);
        }
    }
}

extern "C" void kernel_launch(void* const* d_in, const int* in_sizes, int n_in,
                              void* d_out, int out_size, void* d_ws, size_t ws_size,
                              hipStream_t stream)
{
    const float* x  = (const float*)d_in[0];
    const float* tk = (const float*)d_in[1];
    const float* tq = (const float*)d_in[2];
    const float* tv = (const float*)d_in[3];
    const float* un = (const float*)d_in[4];
    const int* esub  = (const int*)d_in[5];
    const int* epred = (const int*)d_in[6];
    const int* eobj  = (const int*)d_in[7];
    float* out = (float*)d_out;

    // Workspace layout (bytes), top = 214,547,072 < proven 214,662,144:
    //   B1:   [R][N][128] fp32 (K -> AGG, rewritten fully)   @ 0           (102,400,000)
    //   B2:   [R][N][128] fp32 (Q -> V)                      @ 102,400,000 (102,400,000)
    //   EX:   [E][H] fp32                                    @ 204,800,000 (  6,400,000)
    //   HIST/CURSOR: [200000] int                            @ 211,200,000 (    800,000)
    //   SUMS: [196] int (pad 4096)                           @ 212,000,000 (      4,096)
    //   SOFF: [196] int (pad 4096)                           @ 212,004,096 (      4,096)
    //   OFFS: [200001] int                                   @ 212,008,192 (    800,004 pad->807,808)
    //   EIDS: [400000] int                                   @ 212,816,000 (  1,600,000)
    //   Ub:   [R][128][128] bf16                             @ 214,416,000 (    131,072)
    char* ws = (char*)d_ws;
    float* B1   = (float*)(ws);
    float* B2   = (float*)(ws + 102400000);
    float* EX   = (float*)(ws + 204800000);
    int*   HIST = (int*)  (ws + 211200000);      // reused as CURSOR after scan
    int*   SUMS = (int*)  (ws + 212000000);
    int*   SOFF = (int*)  (ws + 212004096);
    int*   OFFS = (int*)  (ws + 212008192);
    int*   EIDS = (int*)  (ws + 212816000);
    unsigned short* Ub = (unsigned short*)(ws + 214416000);

    cast_u<<<256, 256, 0, stream>>>(un, Ub);

    // CSR build (independent of K/Q/V)
    hipMemsetAsync(HIST, 0, N_ROWS * sizeof(int), stream);
    hist_kernel<<<(N_EDGE + 255) / 256, 256, 0, stream>>>(esub, epred, HIST);
    scan_p1<<<196, 256, 0, stream>>>(HIST, SUMS);
    scan_p2<<<1, 256, 0, stream>>>(SUMS, SOFF, OFFS);
    scan_p3<<<196, 256, 0, stream>>>(HIST, SOFF, OFFS);
    cursor_copy<<<(N_ROWS + 255) / 256, 256, 0, stream>>>(OFFS, HIST);   // HIST -> CURSOR
    scatter_kernel<<<(N_EDGE + 255) / 256, 256, 0, stream>>>(esub, epred, HIST, EIDS);

    dim3 pg((N_NODES + 63) / 64, N_REL);
    proj_kernel<true><<<pg, 256, 0, stream>>>(x, tk, tq, B1, B2);   // K -> B1, Q -> B2
    edge_dot_kernel<<<(N_EDGE * N_HEAD) / 256, 256, 0, stream>>>(esub, epred, eobj, B1, B2, EX);

    proj_kernel<false><<<pg, 256, 0, stream>>>(x, tv, nullptr, B2, nullptr);  // V -> B2 (Q dead)

    agg_csr<<<N_ROWS / 4, 256, 0, stream>>>(eobj, OFFS, EIDS, B2, EX, B1);    // AGG -> B1 (K dead)

    unify_mfma<<<(N_NODES + 63) / 64, 256, 0, stream>>>(B1, Ub, out);
}

// Round 7
// 346.384 us; speedup vs baseline: 3.5314x; 1.2554x over previous
//
#include <hip/hip_runtime.h>

constexpr int N_NODES = 50000;
constexpr int N_REL   = 4;
constexpr int EMBD    = 128;
constexpr int N_HEAD  = 4;
constexpr int HS      = 32;
constexpr int N_EDGE  = 400000;
constexpr int N_ROWS  = N_REL * N_NODES;        // 200000 segment rows

typedef __attribute__((ext_vector_type(8))) short bf16x8;
typedef __attribute__((ext_vector_type(4))) float f32x4;
typedef unsigned short ushort_t;

__device__ __forceinline__ float b2f(ushort_t u) {
    return __uint_as_float(((unsigned int)u) << 16);
}
__device__ __forceinline__ ushort_t f2b(float f) {
    unsigned int u = __float_as_uint(f);
    u += 0x7FFF + ((u >> 16) & 1);   // round-to-nearest-even
    return (ushort_t)(u >> 16);
}

// ---------------------------------------------------------------------------
// K/Q/V projection (per-head 32x32 block-diagonal). Structure KNOWN GOOD
// (rounds 2-6); outputs now stored bf16 (compute stays fp32). Wave's 64
// consecutive-j 2B stores = 128B contiguous per row-op.
// ---------------------------------------------------------------------------
template<bool DUAL>
__global__ __launch_bounds__(256) void proj_kernel(
    const float* __restrict__ x,
    const float* __restrict__ W1,
    const float* __restrict__ W2,
    ushort_t* __restrict__ P1, ushort_t* __restrict__ P2)
{
    const int r    = blockIdx.y;
    const int n0   = blockIdx.x * 64;
    const int t    = threadIdx.x;
    const int j    = t & 127;
    const int half = t >> 7;
    const int h    = j >> 5;
    const int s    = j & 31;

    __shared__ float xs[64 * 128];
    {
        const float4* x4 = (const float4*)(x + (size_t)n0 * 128);
        float4* xs4 = (float4*)xs;
        for (int idx = t; idx < 64 * 32; idx += 256) {
            int n = n0 + (idx >> 5);
            float4 v = make_float4(0.f, 0.f, 0.f, 0.f);
            if (n < N_NODES) v = x4[idx];
            xs4[idx] = v;
        }
    }

    float w1[32], w2[32];
    {
        const float* w1p = W1 + (((r * N_HEAD + h) * HS + s) * HS);
        #pragma unroll
        for (int k = 0; k < 32; k++) w1[k] = w1p[k];
        if (DUAL) {
            const float* w2p = W2 + (((r * N_HEAD + h) * HS + s) * HS);
            #pragma unroll
            for (int k = 0; k < 32; k++) w2[k] = w2p[k];
        }
    }
    __syncthreads();

    #pragma unroll 1
    for (int i = 0; i < 32; i++) {
        int n = n0 + half * 32 + i;
        if (n >= N_NODES) break;               // uniform within wave
        const float* xp = &xs[(half * 32 + i) * 128 + h * 32];
        float a1 = 0.f, a2 = 0.f;
        #pragma unroll
        for (int k = 0; k < 32; k++) {
            float xv = xp[k];
            a1 += w1[k] * xv;
            if (DUAL) a2 += w2[k] * xv;
        }
        size_t o = ((size_t)r * N_NODES + n) * 128 + j;
        P1[o] = f2b(a1);
        if (DUAL) P2[o] = f2b(a2);
    }
}

// ---------------------------------------------------------------------------
// Ub[r][i][j] = bf16(unify[r][i][j]). KNOWN GOOD. 128 KB, L2-hot.
// ---------------------------------------------------------------------------
__global__ __launch_bounds__(256) void cast_u(
    const float* __restrict__ U, ushort_t* __restrict__ Ub)
{
    int idx = blockIdx.x * 256 + threadIdx.x;      // 256*256 = 65536 exact
    Ub[idx] = f2b(U[idx]);
}

// ---------------------------------------------------------------------------
// One thread per (edge, head): EX = exp(dot(K,Q)), bf16 operands, fp32 math.
// Lanes 4e..4e+3 read one K row (256B = 2 L2 lines) contiguously — no waste.
// ---------------------------------------------------------------------------
__global__ __launch_bounds__(256) void edge_dot_kernel(
    const int* __restrict__ esub, const int* __restrict__ epred, const int* __restrict__ eobj,
    const ushort_t* __restrict__ K, const ushort_t* __restrict__ Q,
    float* __restrict__ EX)
{
    int gid = blockIdx.x * 256 + threadIdx.x;          // exact: 6250*256 == E*H
    int e = gid >> 2, h = gid & 3;
    int pred = epred[e], sub = esub[e], obj = eobj[e];
    const uint4* kp = (const uint4*)(K + ((size_t)pred * N_NODES + sub) * 128 + h * 32);
    const uint4* qp = (const uint4*)(Q + ((size_t)pred * N_NODES + obj) * 128 + h * 32);
    float dot = 0.f;
    #pragma unroll
    for (int c = 0; c < 4; c++) {                      // 4 x 8 bf16 = 32
        uint4 kv = kp[c], qv = qp[c];
        const ushort_t* ka = (const ushort_t*)&kv;
        const ushort_t* qa = (const ushort_t*)&qv;
        #pragma unroll
        for (int k = 0; k < 8; k++) dot += b2f(ka[k]) * b2f(qa[k]);
    }
    EX[gid] = __expf(dot);
}

// ---------------------------------------------------------------------------
// CSR build: histogram -> 3-phase deterministic scan -> scatter. KNOWN GOOD.
// ---------------------------------------------------------------------------
__global__ __launch_bounds__(256) void hist_kernel(
    const int* __restrict__ esub, const int* __restrict__ epred, int* __restrict__ HIST)
{
    int e = blockIdx.x * 256 + threadIdx.x;
    if (e < N_EDGE) atomicAdd(&HIST[epred[e] * N_NODES + esub[e]], 1);
}

__global__ __launch_bounds__(256) void scan_p1(      // per-block totals
    const int* __restrict__ HIST, int* __restrict__ SUMS)
{
    int b = blockIdx.x, t = threadIdx.x;
    int base = b * 1024 + t * 4;
    int s = 0;
    #pragma unroll
    for (int k = 0; k < 4; k++) if (base + k < N_ROWS) s += HIST[base + k];
    __shared__ int red[256];
    red[t] = s; __syncthreads();
    for (int st = 128; st > 0; st >>= 1) {
        if (t < st) red[t] += red[t + st];
        __syncthreads();
    }
    if (t == 0) SUMS[b] = red[0];
}

__global__ __launch_bounds__(256) void scan_p2(      // scan the 196 totals
    const int* __restrict__ SUMS, int* __restrict__ SOFF, int* __restrict__ OFFS)
{
    int t = threadIdx.x;
    __shared__ int sh[256];
    int o = (t < 196) ? SUMS[t] : 0;
    sh[t] = o; __syncthreads();
    for (int st = 1; st < 256; st <<= 1) {
        int v = (t >= st) ? sh[t - st] : 0;
        __syncthreads();
        sh[t] += v;
        __syncthreads();
    }
    if (t < 196) SOFF[t] = sh[t] - o;                // exclusive
    if (t == 0)  OFFS[N_ROWS] = sh[255];             // total == N_EDGE
}

__global__ __launch_bounds__(256) void scan_p3(      // full exclusive scan
    const int* __restrict__ HIST, const int* __restrict__ SOFF, int* __restrict__ OFFS)
{
    int b = blockIdx.x, t = threadIdx.x;
    int base = b * 1024 + t * 4;
    int v[4], tot = 0;
    #pragma unroll
    for (int k = 0; k < 4; k++) {
        v[k] = (base + k < N_ROWS) ? HIST[base + k] : 0;
        tot += v[k];
    }
    __shared__ int sh[256];
    sh[t] = tot; __syncthreads();
    for (int st = 1; st < 256; st <<= 1) {
        int q = (t >= st) ? sh[t - st] : 0;
        __syncthreads();
        sh[t] += q;
        __syncthreads();
    }
    int run = SOFF[b] + (sh[t] - tot);
    #pragma unroll
    for (int k = 0; k < 4; k++) {
        if (base + k < N_ROWS) { OFFS[base + k] = run; run += v[k]; }
    }
}

__global__ __launch_bounds__(256) void cursor_copy(
    const int* __restrict__ OFFS, int* __restrict__ CURSOR)
{
    int i = blockIdx.x * 256 + threadIdx.x;
    if (i < N_ROWS) CURSOR[i] = OFFS[i];
}

__global__ __launch_bounds__(256) void scatter_kernel(
    const int* __restrict__ esub, const int* __restrict__ epred,
    int* __restrict__ CURSOR, int* __restrict__ EIDS)
{
    int e = blockIdx.x * 256 + threadIdx.x;
    if (e < N_EDGE) {
        int row = epred[e] * N_NODES + esub[e];
        int pos = atomicAdd(&CURSOR[row], 1);
        EIDS[pos] = e;
    }
}

// ---------------------------------------------------------------------------
// One WAVE per row, CSR-driven. bf16 V reads (lane j / j+64: lanes 0-63 cover
// one 128B line each half). Softmax denominator summed in registers,
// normalized output written ONCE as bf16 (zero fp atomics; empty rows -> 0).
// ---------------------------------------------------------------------------
__global__ __launch_bounds__(256) void agg_csr(
    const int* __restrict__ eobj, const int* __restrict__ OFFS, const int* __restrict__ EIDS,
    const ushort_t* __restrict__ V, const float* __restrict__ EX,
    ushort_t* __restrict__ AGG)
{
    const int t    = threadIdx.x;
    const int lane = t & 63;
    const int row  = blockIdx.x * 4 + (t >> 6);     // exact: 50000*4 == N_ROWS
    const int pred = row / N_NODES;                 // wave-uniform
    const int hA   = lane >> 5;                     // head of j=lane (0/1); j+64 -> hA+2

    const int beg = OFFS[row], end = OFFS[row + 1];

    float accA = 0.f, accB = 0.f, segA = 0.f, segB = 0.f;
    for (int i = beg; i < end; i++) {
        int e   = EIDS[i];
        int obj = eobj[e];
        float exA = EX[e * 4 + hA];
        float exB = EX[e * 4 + 2 + hA];
        const ushort_t* vp = V + ((size_t)pred * N_NODES + obj) * 128;
        accA += exA * b2f(vp[lane]);
        accB += exB * b2f(vp[lane + 64]);
        segA += exA;
        segB += exB;
    }
    float invA = (segA > 0.f) ? 1.0f / segA : 0.f;   // empty row -> 0, not NaN
    float invB = (segB > 0.f) ? 1.0f / segB : 0.f;
    ushort_t* op = AGG + (size_t)row * 128;
    op[lane]      = f2b(accA * invA);
    op[lane + 64] = f2b(accB * invB);
}

// ---------------------------------------------------------------------------
// out[n][i] = relu( sum_r sum_j U[r][i][j] * AGGnorm[r][n][j] )  — bf16 MFMA,
// fp32 accum. KNOWN GOOD (rounds 5-6); A-staging is now a plain bf16 copy.
// ---------------------------------------------------------------------------
__global__ __launch_bounds__(256) void unify_mfma(
    const ushort_t* __restrict__ AGG,
    const ushort_t* __restrict__ Ub, float* __restrict__ out)
{
    __shared__ ushort_t As[64 * 136];    // A tile: [node][k] bf16 (stride 272B = 17*16 ✓)
    __shared__ ushort_t Bs[128 * 136];   // B tile: [i][k] bf16

    const int t    = threadIdx.x;
    const int lane = t & 63;
    const int w    = t >> 6;
    const int n0   = blockIdx.x * 64;

    f32x4 acc[8];
    #pragma unroll
    for (int f = 0; f < 8; f++) acc[f] = (f32x4){0.f, 0.f, 0.f, 0.f};

    for (int r = 0; r < N_REL; r++) {
        __syncthreads();

        {   // stage A: AGG[r][n0..n0+63][0..127] plain bf16 copy (16B chunks)
            const uint4* a4 = (const uint4*)(AGG + ((size_t)r * N_NODES + n0) * 128);
            for (int idx = t; idx < 64 * 16; idx += 256) {
                int nn = idx >> 4, c = idx & 15;
                uint4 v = make_uint4(0, 0, 0, 0);
                if (n0 + nn < N_NODES) v = a4[idx];
                *(uint4*)&As[nn * 136 + c * 8] = v;
            }
        }
        {   // stage B: Ub[r] straight copy (L2-hot)
            const uint4* u4 = (const uint4*)(Ub + (size_t)r * 128 * 128);
            for (int idx = t; idx < 128 * 16; idx += 256) {
                int i = idx >> 4, c = idx & 15;
                *(uint4*)&Bs[i * 136 + c * 8] = u4[idx];
            }
        }
        __syncthreads();

        const int row = lane & 15;     // A row / B col
        const int kg  = lane >> 4;     // k-group
        #pragma unroll
        for (int ks = 0; ks < 4; ks++) {
            const int kofs = ks * 32 + kg * 8;
            bf16x8 a = *(const bf16x8*)&As[(w * 16 + row) * 136 + kofs];
            #pragma unroll
            for (int f = 0; f < 8; f++) {
                bf16x8 b = *(const bf16x8*)&Bs[(f * 16 + row) * 136 + kofs];
                acc[f] = __builtin_amdgcn_mfma_f32_16x16x32_bf16(a, b, acc[f], 0, 0, 0);
            }
        }
    }

    const int col  = lane & 15;
    const int rgrp = lane >> 4;
    #pragma unroll
    for (int f = 0; f < 8; f++) {
        #pragma unroll
        for (int reg = 0; reg < 4; reg++) {
            int n = n0 + w * 16 + rgrp * 4 + reg;
            if (n < N_NODES)
                out[(size_t)n * 128 + f * 16 + col] = fmaxf(acc[f][reg], 0.f);
        }
    }
}

extern "C" void kernel_launch(void* const* d_in, const int* in_sizes, int n_in,
                              void* d_out, int out_size, void* d_ws, size_t ws_size,
                              hipStream_t stream)
{
    const float* x  = (const float*)d_in[0];
    const float* tk = (const float*)d_in[1];
    const float* tq = (const float*)d_in[2];
    const float* tv = (const float*)d_in[3];
    const float* un = (const float*)d_in[4];
    const int* esub  = (const int*)d_in[5];
    const int* epred = (const int*)d_in[6];
    const int* eobj  = (const int*)d_in[7];
    float* out = (float*)d_out;

    // Workspace layout (bytes), top = 112,147,072 (well under proven 214.66 MB):
    //   BK:   [R][N][128] bf16 (K, then V overwrites)    @ 0           (51,200,000)
    //   BQ:   [R][N][128] bf16 (Q, then AGG overwrites)  @ 51,200,000  (51,200,000)
    //   EX:   [E][H] fp32                                @ 102,400,000 ( 6,400,000)
    //   HIST/CURSOR: [200000] int                        @ 108,800,000 (   800,000)
    //   SUMS: [196] int (pad 4096)                       @ 109,600,000 (     4,096)
    //   SOFF: [196] int (pad 4096)                       @ 109,604,096 (     4,096)
    //   OFFS: [200001] int                               @ 109,608,192 (   800,004 pad->807,808)
    //   EIDS: [400000] int                               @ 110,416,000 ( 1,600,000)
    //   Ub:   [R][128][128] bf16                         @ 112,016,000 (   131,072)
    char* ws = (char*)d_ws;
    ushort_t* BK  = (ushort_t*)(ws);
    ushort_t* BQ  = (ushort_t*)(ws + 51200000);
    float*    EX  = (float*)   (ws + 102400000);
    int*      HIST= (int*)     (ws + 108800000);   // reused as CURSOR after scan
    int*      SUMS= (int*)     (ws + 109600000);
    int*      SOFF= (int*)     (ws + 109604096);
    int*      OFFS= (int*)     (ws + 109608192);
    int*      EIDS= (int*)     (ws + 110416000);
    ushort_t* Ub  = (ushort_t*)(ws + 112016000);

    cast_u<<<256, 256, 0, stream>>>(un, Ub);

    // CSR build (independent of K/Q/V)
    hipMemsetAsync(HIST, 0, N_ROWS * sizeof(int), stream);
    hist_kernel<<<(N_EDGE + 255) / 256, 256, 0, stream>>>(esub, epred, HIST);
    scan_p1<<<196, 256, 0, stream>>>(HIST, SUMS);
    scan_p2<<<1, 256, 0, stream>>>(SUMS, SOFF, OFFS);
    scan_p3<<<196, 256, 0, stream>>>(HIST, SOFF, OFFS);
    cursor_copy<<<(N_ROWS + 255) / 256, 256, 0, stream>>>(OFFS, HIST);   // HIST -> CURSOR
    scatter_kernel<<<(N_EDGE + 255) / 256, 256, 0, stream>>>(esub, epred, HIST, EIDS);

    dim3 pg((N_NODES + 63) / 64, N_REL);
    proj_kernel<true><<<pg, 256, 0, stream>>>(x, tk, tq, BK, BQ);   // K -> BK, Q -> BQ
    edge_dot_kernel<<<(N_EDGE * N_HEAD) / 256, 256, 0, stream>>>(esub, epred, eobj, BK, BQ, EX);

    proj_kernel<false><<<pg, 256, 0, stream>>>(x, tv, nullptr, BK, nullptr);  // V -> BK (K dead)

    agg_csr<<<N_ROWS / 4, 256, 0, stream>>>(eobj, OFFS, EIDS, BK, EX, BQ);    // AGG -> BQ (Q dead)

    unify_mfma<<<(N_NODES + 63) / 64, 256, 0, stream>>>(BQ, Ub, out);
}

// Round 8
// 250.130 us; speedup vs baseline: 4.8904x; 1.3848x over previous
//
#include <hip/hip_runtime.h>

constexpr int N_NODES = 50000;
constexpr int N_REL   = 4;
constexpr int EMBD    = 128;
constexpr int N_HEAD  = 4;
constexpr int HS      = 32;
constexpr int N_EDGE  = 400000;
constexpr int N_ROWS  = N_REL * N_NODES;        // 200000 segment rows

typedef __attribute__((ext_vector_type(8))) short bf16x8;
typedef __attribute__((ext_vector_type(4))) float f32x4;
typedef unsigned short ushort_t;

__device__ __forceinline__ float b2f(ushort_t u) {
    return __uint_as_float(((unsigned int)u) << 16);
}
__device__ __forceinline__ ushort_t f2b(float f) {
    unsigned int u = __float_as_uint(f);
    u += 0x7FFF + ((u >> 16) & 1);   // round-to-nearest-even
    return (ushort_t)(u >> 16);
}

// ---------------------------------------------------------------------------
// Wb[m][r][h][s][k] = bf16 of {tokeys,toqueries,tovals}[r][h][s][k], m=0/1/2.
// 98 KB total, L2-hot; read as MFMA B-fragments directly from global.
// ---------------------------------------------------------------------------
__global__ __launch_bounds__(256) void cast_w(
    const float* __restrict__ tk, const float* __restrict__ tq,
    const float* __restrict__ tv, ushort_t* __restrict__ Wb)
{
    int idx = blockIdx.x * 256 + threadIdx.x;     // 192*256 = 49152 exact
    int m = idx >> 14, i = idx & 16383;
    const float* src = (m == 0) ? tk : (m == 1) ? tq : tv;
    Wb[idx] = f2b(src[i]);
}

// ---------------------------------------------------------------------------
// Ub[r][i][j] = bf16(unify[r][i][j]). KNOWN GOOD. 128 KB, L2-hot.
// ---------------------------------------------------------------------------
__global__ __launch_bounds__(256) void cast_u(
    const float* __restrict__ U, ushort_t* __restrict__ Ub)
{
    int idx = blockIdx.x * 256 + threadIdx.x;      // 256*256 = 65536 exact
    Ub[idx] = f2b(U[idx]);
}

// ---------------------------------------------------------------------------
// MFMA projection: K/Q/V for all 4 relations in ONE pass over x.
// P_m[r][n][j] = sum_k W_m[r][h(j)][s(j)][k] * x[n][h*32+k].
// Block-diagonal weights => output frag f (head h=f>>1) needs only k-slice h:
// exactly ONE mfma_f32_16x16x32_bf16 per 16x16 output frag (no wasted FLOPs).
// Block: 128 nodes, 8 waves; wave w owns nodes [16w,16w+16) x all 128 j.
// A: x tile bf16 in LDS (f2b on stage). B: 16B/lane loads from L2-hot Wb.
// Replaces the two scalar proj launches (~210us, VALU-bound at 50% busy).
// Fragment maps (m89-verified, proven in unify_mfma rounds 5-7):
//   A row=lane&15, k=8*(lane>>4)+j ; B col=lane&15, same k ;
//   D col=lane&15, row=4*(lane>>4)+reg.
// ---------------------------------------------------------------------------
__global__ __launch_bounds__(512) void proj_mfma(
    const float* __restrict__ x, const ushort_t* __restrict__ Wb,
    ushort_t* __restrict__ K, ushort_t* __restrict__ Q, ushort_t* __restrict__ V)
{
    __shared__ ushort_t xs[128 * 136];   // [node][k] bf16, stride 272B

    const int t    = threadIdx.x;        // 0..511
    const int lane = t & 63;
    const int w    = t >> 6;             // wave 0..7
    const int n0   = blockIdx.x * 128;

    {   // stage x (fp32 global) -> bf16 LDS
        const float4* x4 = (const float4*)(x + (size_t)n0 * 128);
        for (int idx = t; idx < 128 * 32; idx += 512) {
            int nn = idx >> 5, c4 = idx & 31;
            float4 v = make_float4(0.f, 0.f, 0.f, 0.f);
            if (n0 + nn < N_NODES) v = x4[idx];
            ushort4 b = make_ushort4(f2b(v.x), f2b(v.y), f2b(v.z), f2b(v.w));
            *(ushort4*)&xs[nn * 136 + c4 * 4] = b;
        }
    }
    __syncthreads();

    const int row  = lane & 15;     // A node-row / B col / D col
    const int kg   = lane >> 4;     // k-group (8 elems each)
    const int rgrp = lane >> 4;     // D row-group

    #pragma unroll
    for (int m = 0; m < 3; m++) {
        ushort_t* P = (m == 0) ? K : (m == 1) ? Q : V;
        #pragma unroll 1
        for (int r = 0; r < N_REL; r++) {
            f32x4 acc[8];
            #pragma unroll
            for (int f = 0; f < 8; f++) {
                const int h = f >> 1;
                bf16x8 a = *(const bf16x8*)&xs[(w * 16 + row) * 136 + h * 32 + kg * 8];
                const ushort_t* bp = Wb + ((((m * 4 + r) * 4 + h) * 32 + (f & 1) * 16 + row) * 32) + kg * 8;
                bf16x8 b = *(const bf16x8*)bp;
                acc[f] = __builtin_amdgcn_mfma_f32_16x16x32_bf16(
                             a, b, (f32x4){0.f, 0.f, 0.f, 0.f}, 0, 0, 0);
            }
            #pragma unroll
            for (int f = 0; f < 8; f++) {
                #pragma unroll
                for (int reg = 0; reg < 4; reg++) {
                    int n = n0 + w * 16 + rgrp * 4 + reg;
                    if (n < N_NODES)
                        P[((size_t)r * N_NODES + n) * 128 + f * 16 + row] = f2b(acc[f][reg]);
                }
            }
        }
    }
}

// ---------------------------------------------------------------------------
// One thread per (edge, head): EX = exp(dot(K,Q)), bf16 operands, fp32 math.
// KNOWN GOOD (round 7). Lanes 4e..4e+3 cover one K row (256B) contiguously.
// ---------------------------------------------------------------------------
__global__ __launch_bounds__(256) void edge_dot_kernel(
    const int* __restrict__ esub, const int* __restrict__ epred, const int* __restrict__ eobj,
    const ushort_t* __restrict__ K, const ushort_t* __restrict__ Q,
    float* __restrict__ EX)
{
    int gid = blockIdx.x * 256 + threadIdx.x;          // exact: 6250*256 == E*H
    int e = gid >> 2, h = gid & 3;
    int pred = epred[e], sub = esub[e], obj = eobj[e];
    const uint4* kp = (const uint4*)(K + ((size_t)pred * N_NODES + sub) * 128 + h * 32);
    const uint4* qp = (const uint4*)(Q + ((size_t)pred * N_NODES + obj) * 128 + h * 32);
    float dot = 0.f;
    #pragma unroll
    for (int c = 0; c < 4; c++) {                      // 4 x 8 bf16 = 32
        uint4 kv = kp[c], qv = qp[c];
        const ushort_t* ka = (const ushort_t*)&kv;
        const ushort_t* qa = (const ushort_t*)&qv;
        #pragma unroll
        for (int k = 0; k < 8; k++) dot += b2f(ka[k]) * b2f(qa[k]);
    }
    EX[gid] = __expf(dot);
}

// ---------------------------------------------------------------------------
// CSR build: histogram -> 3-phase deterministic scan -> scatter. KNOWN GOOD.
// ---------------------------------------------------------------------------
__global__ __launch_bounds__(256) void hist_kernel(
    const int* __restrict__ esub, const int* __restrict__ epred, int* __restrict__ HIST)
{
    int e = blockIdx.x * 256 + threadIdx.x;
    if (e < N_EDGE) atomicAdd(&HIST[epred[e] * N_NODES + esub[e]], 1);
}

__global__ __launch_bounds__(256) void scan_p1(      // per-block totals
    const int* __restrict__ HIST, int* __restrict__ SUMS)
{
    int b = blockIdx.x, t = threadIdx.x;
    int base = b * 1024 + t * 4;
    int s = 0;
    #pragma unroll
    for (int k = 0; k < 4; k++) if (base + k < N_ROWS) s += HIST[base + k];
    __shared__ int red[256];
    red[t] = s; __syncthreads();
    for (int st = 128; st > 0; st >>= 1) {
        if (t < st) red[t] += red[t + st];
        __syncthreads();
    }
    if (t == 0) SUMS[b] = red[0];
}

__global__ __launch_bounds__(256) void scan_p2(      // scan the 196 totals
    const int* __restrict__ SUMS, int* __restrict__ SOFF, int* __restrict__ OFFS)
{
    int t = threadIdx.x;
    __shared__ int sh[256];
    int o = (t < 196) ? SUMS[t] : 0;
    sh[t] = o; __syncthreads();
    for (int st = 1; st < 256; st <<= 1) {
        int v = (t >= st) ? sh[t - st] : 0;
        __syncthreads();
        sh[t] += v;
        __syncthreads();
    }
    if (t < 196) SOFF[t] = sh[t] - o;                // exclusive
    if (t == 0)  OFFS[N_ROWS] = sh[255];             // total == N_EDGE
}

__global__ __launch_bounds__(256) void scan_p3(      // full exclusive scan
    const int* __restrict__ HIST, const int* __restrict__ SOFF, int* __restrict__ OFFS)
{
    int b = blockIdx.x, t = threadIdx.x;
    int base = b * 1024 + t * 4;
    int v[4], tot = 0;
    #pragma unroll
    for (int k = 0; k < 4; k++) {
        v[k] = (base + k < N_ROWS) ? HIST[base + k] : 0;
        tot += v[k];
    }
    __shared__ int sh[256];
    sh[t] = tot; __syncthreads();
    for (int st = 1; st < 256; st <<= 1) {
        int q = (t >= st) ? sh[t - st] : 0;
        __syncthreads();
        sh[t] += q;
        __syncthreads();
    }
    int run = SOFF[b] + (sh[t] - tot);
    #pragma unroll
    for (int k = 0; k < 4; k++) {
        if (base + k < N_ROWS) { OFFS[base + k] = run; run += v[k]; }
    }
}

__global__ __launch_bounds__(256) void cursor_copy(
    const int* __restrict__ OFFS, int* __restrict__ CURSOR)
{
    int i = blockIdx.x * 256 + threadIdx.x;
    if (i < N_ROWS) CURSOR[i] = OFFS[i];
}

__global__ __launch_bounds__(256) void scatter_kernel(
    const int* __restrict__ esub, const int* __restrict__ epred,
    int* __restrict__ CURSOR, int* __restrict__ EIDS)
{
    int e = blockIdx.x * 256 + threadIdx.x;
    if (e < N_EDGE) {
        int row = epred[e] * N_NODES + esub[e];
        int pos = atomicAdd(&CURSOR[row], 1);
        EIDS[pos] = e;
    }
}

// ---------------------------------------------------------------------------
// One WAVE per row, CSR-driven. KNOWN GOOD (round 7). Register softmax
// denominator, single bf16 write per row, zero fp atomics.
// ---------------------------------------------------------------------------
__global__ __launch_bounds__(256) void agg_csr(
    const int* __restrict__ eobj, const int* __restrict__ OFFS, const int* __restrict__ EIDS,
    const ushort_t* __restrict__ V, const float* __restrict__ EX,
    ushort_t* __restrict__ AGG)
{
    const int t    = threadIdx.x;
    const int lane = t & 63;
    const int row  = blockIdx.x * 4 + (t >> 6);     // exact: 50000*4 == N_ROWS
    const int pred = row / N_NODES;                 // wave-uniform
    const int hA   = lane >> 5;                     // head of j=lane (0/1); j+64 -> hA+2

    const int beg = OFFS[row], end = OFFS[row + 1];

    float accA = 0.f, accB = 0.f, segA = 0.f, segB = 0.f;
    for (int i = beg; i < end; i++) {
        int e   = EIDS[i];
        int obj = eobj[e];
        float exA = EX[e * 4 + hA];
        float exB = EX[e * 4 + 2 + hA];
        const ushort_t* vp = V + ((size_t)pred * N_NODES + obj) * 128;
        accA += exA * b2f(vp[lane]);
        accB += exB * b2f(vp[lane + 64]);
        segA += exA;
        segB += exB;
    }
    float invA = (segA > 0.f) ? 1.0f / segA : 0.f;   // empty row -> 0, not NaN
    float invB = (segB > 0.f) ? 1.0f / segB : 0.f;
    ushort_t* op = AGG + (size_t)row * 128;
    op[lane]      = f2b(accA * invA);
    op[lane + 64] = f2b(accB * invB);
}

// ---------------------------------------------------------------------------
// out[n][i] = relu( sum_r sum_j U[r][i][j] * AGGnorm[r][n][j] )  — bf16 MFMA,
// fp32 accum. KNOWN GOOD (rounds 5-7).
// ---------------------------------------------------------------------------
__global__ __launch_bounds__(256) void unify_mfma(
    const ushort_t* __restrict__ AGG,
    const ushort_t* __restrict__ Ub, float* __restrict__ out)
{
    __shared__ ushort_t As[64 * 136];    // A tile: [node][k] bf16
    __shared__ ushort_t Bs[128 * 136];   // B tile: [i][k] bf16

    const int t    = threadIdx.x;
    const int lane = t & 63;
    const int w    = t >> 6;
    const int n0   = blockIdx.x * 64;

    f32x4 acc[8];
    #pragma unroll
    for (int f = 0; f < 8; f++) acc[f] = (f32x4){0.f, 0.f, 0.f, 0.f};

    for (int r = 0; r < N_REL; r++) {
        __syncthreads();

        {   // stage A: AGG[r][n0..n0+63][0..127] plain bf16 copy (16B chunks)
            const uint4* a4 = (const uint4*)(AGG + ((size_t)r * N_NODES + n0) * 128);
            for (int idx = t; idx < 64 * 16; idx += 256) {
                int nn = idx >> 4, c = idx & 15;
                uint4 v = make_uint4(0, 0, 0, 0);
                if (n0 + nn < N_NODES) v = a4[idx];
                *(uint4*)&As[nn * 136 + c * 8] = v;
            }
        }
        {   // stage B: Ub[r] straight copy (L2-hot)
            const uint4* u4 = (const uint4*)(Ub + (size_t)r * 128 * 128);
            for (int idx = t; idx < 128 * 16; idx += 256) {
                int i = idx >> 4, c = idx & 15;
                *(uint4*)&Bs[i * 136 + c * 8] = u4[idx];
            }
        }
        __syncthreads();

        const int row = lane & 15;     // A row / B col
        const int kg  = lane >> 4;     // k-group
        #pragma unroll
        for (int ks = 0; ks < 4; ks++) {
            const int kofs = ks * 32 + kg * 8;
            bf16x8 a = *(const bf16x8*)&As[(w * 16 + row) * 136 + kofs];
            #pragma unroll
            for (int f = 0; f < 8; f++) {
                bf16x8 b = *(const bf16x8*)&Bs[(f * 16 + row) * 136 + kofs];
                acc[f] = __builtin_amdgcn_mfma_f32_16x16x32_bf16(a, b, acc[f], 0, 0, 0);
            }
        }
    }

    const int col  = lane & 15;
    const int rgrp = lane >> 4;
    #pragma unroll
    for (int f = 0; f < 8; f++) {
        #pragma unroll
        for (int reg = 0; reg < 4; reg++) {
            int n = n0 + w * 16 + rgrp * 4 + reg;
            if (n < N_NODES)
                out[(size_t)n * 128 + f * 16 + col] = fmaxf(acc[f][reg], 0.f);
        }
    }
}

extern "C" void kernel_launch(void* const* d_in, const int* in_sizes, int n_in,
                              void* d_out, int out_size, void* d_ws, size_t ws_size,
                              hipStream_t stream)
{
    const float* x  = (const float*)d_in[0];
    const float* tk = (const float*)d_in[1];
    const float* tq = (const float*)d_in[2];
    const float* tv = (const float*)d_in[3];
    const float* un = (const float*)d_in[4];
    const int* esub  = (const int*)d_in[5];
    const int* epred = (const int*)d_in[6];
    const int* eobj  = (const int*)d_in[7];
    float* out = (float*)d_out;

    // Workspace layout (bytes), top = 163,445,376 (< proven 214.66 MB):
    //   BK:   [R][N][128] bf16 (K)                       @ 0            (51,200,000)
    //   BQ:   [R][N][128] bf16 (Q, then AGG overwrites)  @ 51,200,000   (51,200,000)
    //   BV:   [R][N][128] bf16 (V)                       @ 102,400,000  (51,200,000)
    //   EX:   [E][H] fp32                                @ 153,600,000  ( 6,400,000)
    //   HIST/CURSOR: [200000] int                        @ 160,000,000  (   800,000)
    //   SUMS: [196] int (pad 4096)                       @ 160,800,000  (     4,096)
    //   SOFF: [196] int (pad 4096)                       @ 160,804,096  (     4,096)
    //   OFFS: [200001] int                               @ 160,808,192  (   800,004 pad->807,808)
    //   EIDS: [400000] int                               @ 161,616,000  ( 1,600,000)
    //   Ub:   [R][128][128] bf16                         @ 163,216,000  (   131,072)
    //   Wb:   [3][R][H][32][32] bf16                     @ 163,347,072  (    98,304)
    char* ws = (char*)d_ws;
    ushort_t* BK  = (ushort_t*)(ws);
    ushort_t* BQ  = (ushort_t*)(ws + 51200000);
    ushort_t* BV  = (ushort_t*)(ws + 102400000);
    float*    EX  = (float*)   (ws + 153600000);
    int*      HIST= (int*)     (ws + 160000000);   // reused as CURSOR after scan
    int*      SUMS= (int*)     (ws + 160800000);
    int*      SOFF= (int*)     (ws + 160804096);
    int*      OFFS= (int*)     (ws + 160808192);
    int*      EIDS= (int*)     (ws + 161616000);
    ushort_t* Ub  = (ushort_t*)(ws + 163216000);
    ushort_t* Wb  = (ushort_t*)(ws + 163347072);

    cast_w<<<192, 256, 0, stream>>>(tk, tq, tv, Wb);
    cast_u<<<256, 256, 0, stream>>>(un, Ub);

    // CSR build (independent of K/Q/V)
    hipMemsetAsync(HIST, 0, N_ROWS * sizeof(int), stream);
    hist_kernel<<<(N_EDGE + 255) / 256, 256, 0, stream>>>(esub, epred, HIST);
    scan_p1<<<196, 256, 0, stream>>>(HIST, SUMS);
    scan_p2<<<1, 256, 0, stream>>>(SUMS, SOFF, OFFS);
    scan_p3<<<196, 256, 0, stream>>>(HIST, SOFF, OFFS);
    cursor_copy<<<(N_ROWS + 255) / 256, 256, 0, stream>>>(OFFS, HIST);   // HIST -> CURSOR
    scatter_kernel<<<(N_EDGE + 255) / 256, 256, 0, stream>>>(esub, epred, HIST, EIDS);

    // K/Q/V for all relations in one MFMA pass
    proj_mfma<<<(N_NODES + 127) / 128, 512, 0, stream>>>(x, Wb, BK, BQ, BV);

    edge_dot_kernel<<<(N_EDGE * N_HEAD) / 256, 256, 0, stream>>>(esub, epred, eobj, BK, BQ, EX);

    agg_csr<<<N_ROWS / 4, 256, 0, stream>>>(eobj, OFFS, EIDS, BV, EX, BQ);    // AGG -> BQ (Q dead)

    unify_mfma<<<(N_NODES + 63) / 64, 256, 0, stream>>>(BQ, Ub, out);
}

// Round 9
// 213.609 us; speedup vs baseline: 5.7265x; 1.1710x over previous
//
#include <hip/hip_runtime.h>

constexpr int N_NODES = 50000;
constexpr int N_REL   = 4;
constexpr int EMBD    = 128;
constexpr int N_HEAD  = 4;
constexpr int HS      = 32;
constexpr int N_EDGE  = 400000;
constexpr int N_ROWS  = N_REL * N_NODES;        // 200000 segment rows

typedef __attribute__((ext_vector_type(8))) short bf16x8;
typedef __attribute__((ext_vector_type(4))) float f32x4;
typedef unsigned short ushort_t;

__device__ __forceinline__ float b2f(ushort_t u) {
    return __uint_as_float(((unsigned int)u) << 16);
}
__device__ __forceinline__ ushort_t f2b(float f) {
    unsigned int u = __float_as_uint(f);
    u += 0x7FFF + ((u >> 16) & 1);   // round-to-nearest-even
    return (ushort_t)(u >> 16);
}

// ---------------------------------------------------------------------------
// Wb[m][r][h][s][k] = bf16 of {tokeys,toqueries,tovals}. KNOWN GOOD (r8).
// ---------------------------------------------------------------------------
__global__ __launch_bounds__(256) void cast_w(
    const float* __restrict__ tk, const float* __restrict__ tq,
    const float* __restrict__ tv, ushort_t* __restrict__ Wb)
{
    int idx = blockIdx.x * 256 + threadIdx.x;     // 192*256 = 49152 exact
    int m = idx >> 14, i = idx & 16383;
    const float* src = (m == 0) ? tk : (m == 1) ? tq : tv;
    Wb[idx] = f2b(src[i]);
}

// ---------------------------------------------------------------------------
// Ub[r][i][j] = bf16(unify[r][i][j]). KNOWN GOOD. 128 KB, L2-hot.
// ---------------------------------------------------------------------------
__global__ __launch_bounds__(256) void cast_u(
    const float* __restrict__ U, ushort_t* __restrict__ Ub)
{
    int idx = blockIdx.x * 256 + threadIdx.x;      // 256*256 = 65536 exact
    Ub[idx] = f2b(U[idx]);
}

// ---------------------------------------------------------------------------
// MFMA projection: K/Q/V for all 4 relations in ONE pass over x. KNOWN GOOD (r8).
// ---------------------------------------------------------------------------
__global__ __launch_bounds__(512) void proj_mfma(
    const float* __restrict__ x, const ushort_t* __restrict__ Wb,
    ushort_t* __restrict__ K, ushort_t* __restrict__ Q, ushort_t* __restrict__ V)
{
    __shared__ ushort_t xs[128 * 136];   // [node][k] bf16, stride 272B

    const int t    = threadIdx.x;        // 0..511
    const int lane = t & 63;
    const int w    = t >> 6;             // wave 0..7
    const int n0   = blockIdx.x * 128;

    {   // stage x (fp32 global) -> bf16 LDS
        const float4* x4 = (const float4*)(x + (size_t)n0 * 128);
        for (int idx = t; idx < 128 * 32; idx += 512) {
            int nn = idx >> 5, c4 = idx & 31;
            float4 v = make_float4(0.f, 0.f, 0.f, 0.f);
            if (n0 + nn < N_NODES) v = x4[idx];
            ushort4 b = make_ushort4(f2b(v.x), f2b(v.y), f2b(v.z), f2b(v.w));
            *(ushort4*)&xs[nn * 136 + c4 * 4] = b;
        }
    }
    __syncthreads();

    const int row  = lane & 15;     // A node-row / B col / D col
    const int kg   = lane >> 4;     // k-group (8 elems each)
    const int rgrp = lane >> 4;     // D row-group

    #pragma unroll
    for (int m = 0; m < 3; m++) {
        ushort_t* P = (m == 0) ? K : (m == 1) ? Q : V;
        #pragma unroll 1
        for (int r = 0; r < N_REL; r++) {
            f32x4 acc[8];
            #pragma unroll
            for (int f = 0; f < 8; f++) {
                const int h = f >> 1;
                bf16x8 a = *(const bf16x8*)&xs[(w * 16 + row) * 136 + h * 32 + kg * 8];
                const ushort_t* bp = Wb + ((((m * 4 + r) * 4 + h) * 32 + (f & 1) * 16 + row) * 32) + kg * 8;
                bf16x8 b = *(const bf16x8*)bp;
                acc[f] = __builtin_amdgcn_mfma_f32_16x16x32_bf16(
                             a, b, (f32x4){0.f, 0.f, 0.f, 0.f}, 0, 0, 0);
            }
            #pragma unroll
            for (int f = 0; f < 8; f++) {
                #pragma unroll
                for (int reg = 0; reg < 4; reg++) {
                    int n = n0 + w * 16 + rgrp * 4 + reg;
                    if (n < N_NODES)
                        P[((size_t)r * N_NODES + n) * 128 + f * 16 + row] = f2b(acc[f][reg]);
                }
            }
        }
    }
}

// ---------------------------------------------------------------------------
// CSR build: histogram -> 3-phase deterministic scan -> scatter. KNOWN GOOD.
// scatter now stores OBJ directly (agg never needs the edge id) — removes one
// level of dependent indirection from the hot aggregation loop.
// ---------------------------------------------------------------------------
__global__ __launch_bounds__(256) void hist_kernel(
    const int* __restrict__ esub, const int* __restrict__ epred, int* __restrict__ HIST)
{
    int e = blockIdx.x * 256 + threadIdx.x;
    if (e < N_EDGE) atomicAdd(&HIST[epred[e] * N_NODES + esub[e]], 1);
}

__global__ __launch_bounds__(256) void scan_p1(      // per-block totals
    const int* __restrict__ HIST, int* __restrict__ SUMS)
{
    int b = blockIdx.x, t = threadIdx.x;
    int base = b * 1024 + t * 4;
    int s = 0;
    #pragma unroll
    for (int k = 0; k < 4; k++) if (base + k < N_ROWS) s += HIST[base + k];
    __shared__ int red[256];
    red[t] = s; __syncthreads();
    for (int st = 128; st > 0; st >>= 1) {
        if (t < st) red[t] += red[t + st];
        __syncthreads();
    }
    if (t == 0) SUMS[b] = red[0];
}

__global__ __launch_bounds__(256) void scan_p2(      // scan the 196 totals
    const int* __restrict__ SUMS, int* __restrict__ SOFF, int* __restrict__ OFFS)
{
    int t = threadIdx.x;
    __shared__ int sh[256];
    int o = (t < 196) ? SUMS[t] : 0;
    sh[t] = o; __syncthreads();
    for (int st = 1; st < 256; st <<= 1) {
        int v = (t >= st) ? sh[t - st] : 0;
        __syncthreads();
        sh[t] += v;
        __syncthreads();
    }
    if (t < 196) SOFF[t] = sh[t] - o;                // exclusive
    if (t == 0)  OFFS[N_ROWS] = sh[255];             // total == N_EDGE
}

__global__ __launch_bounds__(256) void scan_p3(      // full exclusive scan
    const int* __restrict__ HIST, const int* __restrict__ SOFF, int* __restrict__ OFFS)
{
    int b = blockIdx.x, t = threadIdx.x;
    int base = b * 1024 + t * 4;
    int v[4], tot = 0;
    #pragma unroll
    for (int k = 0; k < 4; k++) {
        v[k] = (base + k < N_ROWS) ? HIST[base + k] : 0;
        tot += v[k];
    }
    __shared__ int sh[256];
    sh[t] = tot; __syncthreads();
    for (int st = 1; st < 256; st <<= 1) {
        int q = (t >= st) ? sh[t - st] : 0;
        __syncthreads();
        sh[t] += q;
        __syncthreads();
    }
    int run = SOFF[b] + (sh[t] - tot);
    #pragma unroll
    for (int k = 0; k < 4; k++) {
        if (base + k < N_ROWS) { OFFS[base + k] = run; run += v[k]; }
    }
}

__global__ __launch_bounds__(256) void cursor_copy(
    const int* __restrict__ OFFS, int* __restrict__ CURSOR)
{
    int i = blockIdx.x * 256 + threadIdx.x;
    if (i < N_ROWS) CURSOR[i] = OFFS[i];
}

__global__ __launch_bounds__(256) void scatter_kernel(
    const int* __restrict__ esub, const int* __restrict__ epred, const int* __restrict__ eobj,
    int* __restrict__ CURSOR, int* __restrict__ OBJS)
{
    int e = blockIdx.x * 256 + threadIdx.x;
    if (e < N_EDGE) {
        int row = epred[e] * N_NODES + esub[e];
        int pos = atomicAdd(&CURSOR[row], 1);
        OBJS[pos] = eobj[e];                       // store obj, not edge id
    }
}

// ---------------------------------------------------------------------------
// FUSED dot+softmax+aggregate, one WAVE per CSR row:
//   AGG[row][j] = sum_e exp(dot_h(j)) * V[pred,obj_e][j] / sum_e exp(dot_h(j))
// K[row] is wave-uniform -> held in 2 regs/lane (K + row*128 indexes directly).
// Per edge: gather Q[obj] + V[obj] rows (independent 128B-coalesced loads),
// per-head dot via 5 shfl_xor rounds (lanes 0-31 reduce heads 0/2, lanes
// 32-63 heads 1/3 -> per-lane ex matches the j-ownership of the accumulate).
// 2-edge unroll: all 8 gathers issue before any use (one latency round/pair).
// Replaces edge_dot (~55us) + agg_csr (84.5us, chain depth 4); EX buffer gone.
// ---------------------------------------------------------------------------
__global__ __launch_bounds__(256) void agg_fused(
    const int* __restrict__ OFFS, const int* __restrict__ OBJS,
    const ushort_t* __restrict__ K, const ushort_t* __restrict__ Q,
    const ushort_t* __restrict__ V, ushort_t* __restrict__ AGG)
{
    const int t    = threadIdx.x;
    const int lane = t & 63;
    const int row  = blockIdx.x * 4 + (t >> 6);     // exact: 50000*4 == N_ROWS
    const int beg  = OFFS[row], end = OFFS[row + 1];

    ushort_t* op = AGG + (size_t)row * 128;
    if (beg == end) {                                // empty row: zeros, skip K
        op[lane] = 0; op[lane + 64] = 0;
        return;
    }

    const size_t nbase = (size_t)(row / N_NODES) * N_NODES;   // pred*N, wave-uniform
    const float kA = b2f(K[(size_t)row * 128 + lane]);
    const float kB = b2f(K[(size_t)row * 128 + lane + 64]);

    float accA = 0.f, accB = 0.f, segA = 0.f, segB = 0.f;
    int i = beg;
    for (; i + 2 <= end; i += 2) {
        int o0 = OBJS[i], o1 = OBJS[i + 1];
        const ushort_t* q0 = Q + (nbase + o0) * 128;
        const ushort_t* q1 = Q + (nbase + o1) * 128;
        const ushort_t* v0 = V + (nbase + o0) * 128;
        const ushort_t* v1 = V + (nbase + o1) * 128;
        float q0A = b2f(q0[lane]), q0B = b2f(q0[lane + 64]);
        float q1A = b2f(q1[lane]), q1B = b2f(q1[lane + 64]);
        float v0A = b2f(v0[lane]), v0B = b2f(v0[lane + 64]);
        float v1A = b2f(v1[lane]), v1B = b2f(v1[lane + 64]);
        float pA0 = kA * q0A, pB0 = kB * q0B;
        float pA1 = kA * q1A, pB1 = kB * q1B;
        #pragma unroll
        for (int m = 1; m < 32; m <<= 1) {
            pA0 += __shfl_xor(pA0, m, 64);
            pB0 += __shfl_xor(pB0, m, 64);
            pA1 += __shfl_xor(pA1, m, 64);
            pB1 += __shfl_xor(pB1, m, 64);
        }
        float exA0 = __expf(pA0), exB0 = __expf(pB0);
        float exA1 = __expf(pA1), exB1 = __expf(pB1);
        accA += exA0 * v0A + exA1 * v1A;
        accB += exB0 * v0B + exB1 * v1B;
        segA += exA0 + exA1;
        segB += exB0 + exB1;
    }
    if (i < end) {                                   // odd tail
        int o0 = OBJS[i];
        const ushort_t* q0 = Q + (nbase + o0) * 128;
        const ushort_t* v0 = V + (nbase + o0) * 128;
        float q0A = b2f(q0[lane]), q0B = b2f(q0[lane + 64]);
        float v0A = b2f(v0[lane]), v0B = b2f(v0[lane + 64]);
        float pA0 = kA * q0A, pB0 = kB * q0B;
        #pragma unroll
        for (int m = 1; m < 32; m <<= 1) {
            pA0 += __shfl_xor(pA0, m, 64);
            pB0 += __shfl_xor(pB0, m, 64);
        }
        float exA0 = __expf(pA0), exB0 = __expf(pB0);
        accA += exA0 * v0A;
        accB += exB0 * v0B;
        segA += exA0;
        segB += exB0;
    }

    op[lane]      = f2b(accA / segA);    // beg!=end => seg >= exp(dot) > 0
    op[lane + 64] = f2b(accB / segB);
}

// ---------------------------------------------------------------------------
// out[n][i] = relu( sum_r sum_j U[r][i][j] * AGGnorm[r][n][j] )  — bf16 MFMA,
// fp32 accum. KNOWN GOOD (rounds 5-8).
// ---------------------------------------------------------------------------
__global__ __launch_bounds__(256) void unify_mfma(
    const ushort_t* __restrict__ AGG,
    const ushort_t* __restrict__ Ub, float* __restrict__ out)
{
    __shared__ ushort_t As[64 * 136];    // A tile: [node][k] bf16
    __shared__ ushort_t Bs[128 * 136];   // B tile: [i][k] bf16

    const int t    = threadIdx.x;
    const int lane = t & 63;
    const int w    = t >> 6;
    const int n0   = blockIdx.x * 64;

    f32x4 acc[8];
    #pragma unroll
    for (int f = 0; f < 8; f++) acc[f] = (f32x4){0.f, 0.f, 0.f, 0.f};

    for (int r = 0; r < N_REL; r++) {
        __syncthreads();

        {   // stage A: AGG[r][n0..n0+63][0..127] plain bf16 copy (16B chunks)
            const uint4* a4 = (const uint4*)(AGG + ((size_t)r * N_NODES + n0) * 128);
            for (int idx = t; idx < 64 * 16; idx += 256) {
                int nn = idx >> 4, c = idx & 15;
                uint4 v = make_uint4(0, 0, 0, 0);
                if (n0 + nn < N_NODES) v = a4[idx];
                *(uint4*)&As[nn * 136 + c * 8] = v;
            }
        }
        {   // stage B: Ub[r] straight copy (L2-hot)
            const uint4* u4 = (const uint4*)(Ub + (size_t)r * 128 * 128);
            for (int idx = t; idx < 128 * 16; idx += 256) {
                int i = idx >> 4, c = idx & 15;
                *(uint4*)&Bs[i * 136 + c * 8] = u4[idx];
            }
        }
        __syncthreads();

        const int row = lane & 15;     // A row / B col
        const int kg  = lane >> 4;     // k-group
        #pragma unroll
        for (int ks = 0; ks < 4; ks++) {
            const int kofs = ks * 32 + kg * 8;
            bf16x8 a = *(const bf16x8*)&As[(w * 16 + row) * 136 + kofs];
            #pragma unroll
            for (int f = 0; f < 8; f++) {
                bf16x8 b = *(const bf16x8*)&Bs[(f * 16 + row) * 136 + kofs];
                acc[f] = __builtin_amdgcn_mfma_f32_16x16x32_bf16(a, b, acc[f], 0, 0, 0);
            }
        }
    }

    const int col  = lane & 15;
    const int rgrp = lane >> 4;
    #pragma unroll
    for (int f = 0; f < 8; f++) {
        #pragma unroll
        for (int reg = 0; reg < 4; reg++) {
            int n = n0 + w * 16 + rgrp * 4 + reg;
            if (n < N_NODES)
                out[(size_t)n * 128 + f * 16 + col] = fmaxf(acc[f][reg], 0.f);
        }
    }
}

extern "C" void kernel_launch(void* const* d_in, const int* in_sizes, int n_in,
                              void* d_out, int out_size, void* d_ws, size_t ws_size,
                              hipStream_t stream)
{
    const float* x  = (const float*)d_in[0];
    const float* tk = (const float*)d_in[1];
    const float* tq = (const float*)d_in[2];
    const float* tv = (const float*)d_in[3];
    const float* un = (const float*)d_in[4];
    const int* esub  = (const int*)d_in[5];
    const int* epred = (const int*)d_in[6];
    const int* eobj  = (const int*)d_in[7];
    float* out = (float*)d_out;

    // Workspace layout (bytes), same offsets as round 8 (EX slot now unused):
    //   BK:   [R][N][128] bf16 (K)                       @ 0            (51,200,000)
    //   BQ:   [R][N][128] bf16 (Q, then AGG overwrites)  @ 51,200,000   (51,200,000)
    //   BV:   [R][N][128] bf16 (V)                       @ 102,400,000  (51,200,000)
    //   (unused)                                         @ 153,600,000  ( 6,400,000)
    //   HIST/CURSOR: [200000] int                        @ 160,000,000  (   800,000)
    //   SUMS: [196] int (pad 4096)                       @ 160,800,000  (     4,096)
    //   SOFF: [196] int (pad 4096)                       @ 160,804,096  (     4,096)
    //   OFFS: [200001] int                               @ 160,808,192  (   800,004 pad->807,808)
    //   OBJS: [400000] int                               @ 161,616,000  ( 1,600,000)
    //   Ub:   [R][128][128] bf16                         @ 163,216,000  (   131,072)
    //   Wb:   [3][R][H][32][32] bf16                     @ 163,347,072  (    98,304)
    char* ws = (char*)d_ws;
    ushort_t* BK  = (ushort_t*)(ws);
    ushort_t* BQ  = (ushort_t*)(ws + 51200000);
    ushort_t* BV  = (ushort_t*)(ws + 102400000);
    int*      HIST= (int*)     (ws + 160000000);   // reused as CURSOR after scan
    int*      SUMS= (int*)     (ws + 160800000);
    int*      SOFF= (int*)     (ws + 160804096);
    int*      OFFS= (int*)     (ws + 160808192);
    int*      OBJS= (int*)     (ws + 161616000);
    ushort_t* Ub  = (ushort_t*)(ws + 163216000);
    ushort_t* Wb  = (ushort_t*)(ws + 163347072);

    cast_w<<<192, 256, 0, stream>>>(tk, tq, tv, Wb);
    cast_u<<<256, 256, 0, stream>>>(un, Ub);

    // CSR build (independent of K/Q/V)
    hipMemsetAsync(HIST, 0, N_ROWS * sizeof(int), stream);
    hist_kernel<<<(N_EDGE + 255) / 256, 256, 0, stream>>>(esub, epred, HIST);
    scan_p1<<<196, 256, 0, stream>>>(HIST, SUMS);
    scan_p2<<<1, 256, 0, stream>>>(SUMS, SOFF, OFFS);
    scan_p3<<<196, 256, 0, stream>>>(HIST, SOFF, OFFS);
    cursor_copy<<<(N_ROWS + 255) / 256, 256, 0, stream>>>(OFFS, HIST);   // HIST -> CURSOR
    scatter_kernel<<<(N_EDGE + 255) / 256, 256, 0, stream>>>(esub, epred, eobj, HIST, OBJS);

    // K/Q/V for all relations in one MFMA pass
    proj_mfma<<<(N_NODES + 127) / 128, 512, 0, stream>>>(x, Wb, BK, BQ, BV);

    // fused dot + softmax + aggregate (AGG -> BQ after Q is consumed... note:
    // AGG must NOT overwrite BQ while agg_fused still gathers Q from it, so
    // AGG goes to a region whose data is dead: reuse BK? K is read per-row in
    // the same kernel. Use the dedicated dead EX region? Too small (6.4MB vs
    // 51.2MB needed). -> write AGG over BK is unsafe (K read throughout), over
    // BQ unsafe (Q gathered throughout). Solution: AGG gets its own buffer.
    agg_fused<<<N_ROWS / 4, 256, 0, stream>>>(OFFS, OBJS, BK, BQ, BV,
                                              (ushort_t*)(ws + 165000000));

    unify_mfma<<<(N_NODES + 63) / 64, 256, 0, stream>>>((ushort_t*)(ws + 165000000), Ub, out);
}

// Round 10
// 202.024 us; speedup vs baseline: 6.0549x; 1.0573x over previous
//
#include <hip/hip_runtime.h>

constexpr int N_NODES = 50000;
constexpr int N_REL   = 4;
constexpr int EMBD    = 128;
constexpr int N_HEAD  = 4;
constexpr int HS      = 32;
constexpr int N_EDGE  = 400000;
constexpr int N_ROWS  = N_REL * N_NODES;        // 200000 segment rows

typedef __attribute__((ext_vector_type(8))) short bf16x8;
typedef __attribute__((ext_vector_type(4))) float f32x4;
typedef unsigned short ushort_t;

__device__ __forceinline__ float b2f(ushort_t u) {
    return __uint_as_float(((unsigned int)u) << 16);
}
__device__ __forceinline__ ushort_t f2b(float f) {
    unsigned int u = __float_as_uint(f);
    u += 0x7FFF + ((u >> 16) & 1);   // round-to-nearest-even
    return (ushort_t)(u >> 16);
}

// ---------------------------------------------------------------------------
// prep: Wb = bf16({tokeys,toqueries,tovals}), Ub = bf16(unify), HIST = 0.
// Fuses the two cast kernels + hipMemset into one launch.
// ---------------------------------------------------------------------------
__global__ __launch_bounds__(256) void prep_kernel(
    const float* __restrict__ tk, const float* __restrict__ tq,
    const float* __restrict__ tv, const float* __restrict__ un,
    ushort_t* __restrict__ Wb, ushort_t* __restrict__ Ub, int* __restrict__ HIST)
{
    int idx = blockIdx.x * 256 + threadIdx.x;      // grid covers 200192
    if (idx < 49152) {
        int m = idx >> 14, i2 = idx & 16383;
        const float* src = (m == 0) ? tk : (m == 1) ? tq : tv;
        Wb[idx] = f2b(src[i2]);
    }
    if (idx < 65536) Ub[idx] = f2b(un[idx]);
    if (idx < N_ROWS) HIST[idx] = 0;
}

// ---------------------------------------------------------------------------
// MFMA projection: K/Q/V for all 4 relations in ONE pass over x. KNOWN GOOD (r8/9).
// ---------------------------------------------------------------------------
__global__ __launch_bounds__(512) void proj_mfma(
    const float* __restrict__ x, const ushort_t* __restrict__ Wb,
    ushort_t* __restrict__ K, ushort_t* __restrict__ Q, ushort_t* __restrict__ V)
{
    __shared__ ushort_t xs[128 * 136];   // [node][k] bf16, stride 272B

    const int t    = threadIdx.x;        // 0..511
    const int lane = t & 63;
    const int w    = t >> 6;             // wave 0..7
    const int n0   = blockIdx.x * 128;

    {   // stage x (fp32 global) -> bf16 LDS
        const float4* x4 = (const float4*)(x + (size_t)n0 * 128);
        for (int idx = t; idx < 128 * 32; idx += 512) {
            int nn = idx >> 5, c4 = idx & 31;
            float4 v = make_float4(0.f, 0.f, 0.f, 0.f);
            if (n0 + nn < N_NODES) v = x4[idx];
            ushort4 b = make_ushort4(f2b(v.x), f2b(v.y), f2b(v.z), f2b(v.w));
            *(ushort4*)&xs[nn * 136 + c4 * 4] = b;
        }
    }
    __syncthreads();

    const int row  = lane & 15;     // A node-row / B col / D col
    const int kg   = lane >> 4;     // k-group (8 elems each)
    const int rgrp = lane >> 4;     // D row-group

    #pragma unroll
    for (int m = 0; m < 3; m++) {
        ushort_t* P = (m == 0) ? K : (m == 1) ? Q : V;
        #pragma unroll 1
        for (int r = 0; r < N_REL; r++) {
            f32x4 acc[8];
            #pragma unroll
            for (int f = 0; f < 8; f++) {
                const int h = f >> 1;
                bf16x8 a = *(const bf16x8*)&xs[(w * 16 + row) * 136 + h * 32 + kg * 8];
                const ushort_t* bp = Wb + ((((m * 4 + r) * 4 + h) * 32 + (f & 1) * 16 + row) * 32) + kg * 8;
                bf16x8 b = *(const bf16x8*)bp;
                acc[f] = __builtin_amdgcn_mfma_f32_16x16x32_bf16(
                             a, b, (f32x4){0.f, 0.f, 0.f, 0.f}, 0, 0, 0);
            }
            #pragma unroll
            for (int f = 0; f < 8; f++) {
                #pragma unroll
                for (int reg = 0; reg < 4; reg++) {
                    int n = n0 + w * 16 + rgrp * 4 + reg;
                    if (n < N_NODES)
                        P[((size_t)r * N_NODES + n) * 128 + f * 16 + row] = f2b(acc[f][reg]);
                }
            }
        }
    }
}

// ---------------------------------------------------------------------------
// CSR build: histogram -> 3-phase deterministic scan -> scatter. KNOWN GOOD.
// scan_p3 now also writes CURSOR (folds the cursor_copy launch).
// ---------------------------------------------------------------------------
__global__ __launch_bounds__(256) void hist_kernel(
    const int* __restrict__ esub, const int* __restrict__ epred, int* __restrict__ HIST)
{
    int e = blockIdx.x * 256 + threadIdx.x;
    if (e < N_EDGE) atomicAdd(&HIST[epred[e] * N_NODES + esub[e]], 1);
}

__global__ __launch_bounds__(256) void scan_p1(      // per-block totals
    const int* __restrict__ HIST, int* __restrict__ SUMS)
{
    int b = blockIdx.x, t = threadIdx.x;
    int base = b * 1024 + t * 4;
    int s = 0;
    #pragma unroll
    for (int k = 0; k < 4; k++) if (base + k < N_ROWS) s += HIST[base + k];
    __shared__ int red[256];
    red[t] = s; __syncthreads();
    for (int st = 128; st > 0; st >>= 1) {
        if (t < st) red[t] += red[t + st];
        __syncthreads();
    }
    if (t == 0) SUMS[b] = red[0];
}

__global__ __launch_bounds__(256) void scan_p2(      // scan the 196 totals
    const int* __restrict__ SUMS, int* __restrict__ SOFF, int* __restrict__ OFFS)
{
    int t = threadIdx.x;
    __shared__ int sh[256];
    int o = (t < 196) ? SUMS[t] : 0;
    sh[t] = o; __syncthreads();
    for (int st = 1; st < 256; st <<= 1) {
        int v = (t >= st) ? sh[t - st] : 0;
        __syncthreads();
        sh[t] += v;
        __syncthreads();
    }
    if (t < 196) SOFF[t] = sh[t] - o;                // exclusive
    if (t == 0)  OFFS[N_ROWS] = sh[255];             // total == N_EDGE
}

__global__ __launch_bounds__(256) void scan_p3(      // full exclusive scan
    const int* __restrict__ HIST, const int* __restrict__ SOFF,
    int* __restrict__ OFFS, int* __restrict__ CURSOR)
{
    int b = blockIdx.x, t = threadIdx.x;
    int base = b * 1024 + t * 4;
    int v[4], tot = 0;
    #pragma unroll
    for (int k = 0; k < 4; k++) {
        v[k] = (base + k < N_ROWS) ? HIST[base + k] : 0;
        tot += v[k];
    }
    __shared__ int sh[256];
    sh[t] = tot; __syncthreads();
    for (int st = 1; st < 256; st <<= 1) {
        int q = (t >= st) ? sh[t - st] : 0;
        __syncthreads();
        sh[t] += q;
        __syncthreads();
    }
    int run = SOFF[b] + (sh[t] - tot);
    #pragma unroll
    for (int k = 0; k < 4; k++) {
        if (base + k < N_ROWS) { OFFS[base + k] = run; CURSOR[base + k] = run; run += v[k]; }
    }
}

__global__ __launch_bounds__(256) void scatter_kernel(
    const int* __restrict__ esub, const int* __restrict__ epred, const int* __restrict__ eobj,
    int* __restrict__ CURSOR, int* __restrict__ OBJS)
{
    int e = blockIdx.x * 256 + threadIdx.x;
    if (e < N_EDGE) {
        int row = epred[e] * N_NODES + esub[e];
        int pos = atomicAdd(&CURSOR[row], 1);
        OBJS[pos] = eobj[e];                       // store obj, not edge id
    }
}

// ---------------------------------------------------------------------------
// FUSED dot+softmax+aggregate, one WAVE per CSR row.
// NEW lane mapping: lane l -> head g=l>>4, elements j1=g*32+(l&15) and j1+16.
// Both owned elements are in the SAME head =>
//   - dot partial = kA*qA + kB*qB (one fma pair),
//   - butterfly reduce over 16 lanes only: 4 shfl_xor rounds (m=1,2,4,8),
//   - ONE exp and ONE seg accumulator per lane (was 10 shfl + 2 exp / edge).
// 32-bit offsets in hot loop (max elem offset 25.6M << 2^32).
// ---------------------------------------------------------------------------
__global__ __launch_bounds__(256) void agg_fused(
    const int* __restrict__ OFFS, const int* __restrict__ OBJS,
    const ushort_t* __restrict__ K, const ushort_t* __restrict__ Q,
    const ushort_t* __restrict__ V, ushort_t* __restrict__ AGG)
{
    const int t    = threadIdx.x;
    const int lane = t & 63;
    const int row  = blockIdx.x * 4 + (t >> 6);     // exact: 50000*4 == N_ROWS
    const int beg  = OFFS[row], end = OFFS[row + 1];

    const int j1 = (lane >> 4) * 32 + (lane & 15);  // head g = lane>>4; j2 = j1+16

    ushort_t* op = AGG + (size_t)row * 128;
    if (beg == end) {                                // empty row: zeros, skip K
        op[j1] = 0; op[j1 + 16] = 0;
        return;
    }

    const unsigned nbase = (unsigned)(row / N_NODES) * (unsigned)N_NODES;  // wave-uniform
    const float kA = b2f(K[(size_t)row * 128 + j1]);
    const float kB = b2f(K[(size_t)row * 128 + j1 + 16]);

    float accA = 0.f, accB = 0.f, seg = 0.f;
    int i = beg;
    for (; i + 2 <= end; i += 2) {
        unsigned off0 = (nbase + (unsigned)OBJS[i])     * 128u;
        unsigned off1 = (nbase + (unsigned)OBJS[i + 1]) * 128u;
        float q0A = b2f(Q[off0 + j1]), q0B = b2f(Q[off0 + j1 + 16]);
        float v0A = b2f(V[off0 + j1]), v0B = b2f(V[off0 + j1 + 16]);
        float q1A = b2f(Q[off1 + j1]), q1B = b2f(Q[off1 + j1 + 16]);
        float v1A = b2f(V[off1 + j1]), v1B = b2f(V[off1 + j1 + 16]);
        float p0 = kA * q0A + kB * q0B;
        float p1 = kA * q1A + kB * q1B;
        #pragma unroll
        for (int m = 1; m < 16; m <<= 1) {          // 16-lane butterfly
            p0 += __shfl_xor(p0, m, 64);
            p1 += __shfl_xor(p1, m, 64);
        }
        float ex0 = __expf(p0), ex1 = __expf(p1);
        accA += ex0 * v0A + ex1 * v1A;
        accB += ex0 * v0B + ex1 * v1B;
        seg  += ex0 + ex1;
    }
    if (i < end) {                                   // odd tail
        unsigned off0 = (nbase + (unsigned)OBJS[i]) * 128u;
        float q0A = b2f(Q[off0 + j1]), q0B = b2f(Q[off0 + j1 + 16]);
        float v0A = b2f(V[off0 + j1]), v0B = b2f(V[off0 + j1 + 16]);
        float p0 = kA * q0A + kB * q0B;
        #pragma unroll
        for (int m = 1; m < 16; m <<= 1) p0 += __shfl_xor(p0, m, 64);
        float ex0 = __expf(p0);
        accA += ex0 * v0A;
        accB += ex0 * v0B;
        seg  += ex0;
    }

    float inv = 1.0f / seg;                          // beg!=end => seg > 0
    op[j1]      = f2b(accA * inv);
    op[j1 + 16] = f2b(accB * inv);
}

// ---------------------------------------------------------------------------
// out[n][i] = relu( sum_r sum_j U[r][i][j] * AGGnorm[r][n][j] )  — bf16 MFMA,
// fp32 accum. KNOWN GOOD (rounds 5-9).
// ---------------------------------------------------------------------------
__global__ __launch_bounds__(256) void unify_mfma(
    const ushort_t* __restrict__ AGG,
    const ushort_t* __restrict__ Ub, float* __restrict__ out)
{
    __shared__ ushort_t As[64 * 136];    // A tile: [node][k] bf16
    __shared__ ushort_t Bs[128 * 136];   // B tile: [i][k] bf16

    const int t    = threadIdx.x;
    const int lane = t & 63;
    const int w    = t >> 6;
    const int n0   = blockIdx.x * 64;

    f32x4 acc[8];
    #pragma unroll
    for (int f = 0; f < 8; f++) acc[f] = (f32x4){0.f, 0.f, 0.f, 0.f};

    for (int r = 0; r < N_REL; r++) {
        __syncthreads();

        {   // stage A: AGG[r][n0..n0+63][0..127] plain bf16 copy (16B chunks)
            const uint4* a4 = (const uint4*)(AGG + ((size_t)r * N_NODES + n0) * 128);
            for (int idx = t; idx < 64 * 16; idx += 256) {
                int nn = idx >> 4, c = idx & 15;
                uint4 v = make_uint4(0, 0, 0, 0);
                if (n0 + nn < N_NODES) v = a4[idx];
                *(uint4*)&As[nn * 136 + c * 8] = v;
            }
        }
        {   // stage B: Ub[r] straight copy (L2-hot)
            const uint4* u4 = (const uint4*)(Ub + (size_t)r * 128 * 128);
            for (int idx = t; idx < 128 * 16; idx += 256) {
                int i = idx >> 4, c = idx & 15;
                *(uint4*)&Bs[i * 136 + c * 8] = u4[idx];
            }
        }
        __syncthreads();

        const int row = lane & 15;     // A row / B col
        const int kg  = lane >> 4;     // k-group
        #pragma unroll
        for (int ks = 0; ks < 4; ks++) {
            const int kofs = ks * 32 + kg * 8;
            bf16x8 a = *(const bf16x8*)&As[(w * 16 + row) * 136 + kofs];
            #pragma unroll
            for (int f = 0; f < 8; f++) {
                bf16x8 b = *(const bf16x8*)&Bs[(f * 16 + row) * 136 + kofs];
                acc[f] = __builtin_amdgcn_mfma_f32_16x16x32_bf16(a, b, acc[f], 0, 0, 0);
            }
        }
    }

    const int col  = lane & 15;
    const int rgrp = lane >> 4;
    #pragma unroll
    for (int f = 0; f < 8; f++) {
        #pragma unroll
        for (int reg = 0; reg < 4; reg++) {
            int n = n0 + w * 16 + rgrp * 4 + reg;
            if (n < N_NODES)
                out[(size_t)n * 128 + f * 16 + col] = fmaxf(acc[f][reg], 0.f);
        }
    }
}

extern "C" void kernel_launch(void* const* d_in, const int* in_sizes, int n_in,
                              void* d_out, int out_size, void* d_ws, size_t ws_size,
                              hipStream_t stream)
{
    const float* x  = (const float*)d_in[0];
    const float* tk = (const float*)d_in[1];
    const float* tq = (const float*)d_in[2];
    const float* tv = (const float*)d_in[3];
    const float* un = (const float*)d_in[4];
    const int* esub  = (const int*)d_in[5];
    const int* epred = (const int*)d_in[6];
    const int* eobj  = (const int*)d_in[7];
    float* out = (float*)d_out;

    // Workspace layout (bytes), identical offsets to round 9 (proven):
    //   BK:   [R][N][128] bf16 (K)                       @ 0            (51,200,000)
    //   BQ:   [R][N][128] bf16 (Q)                       @ 51,200,000   (51,200,000)
    //   BV:   [R][N][128] bf16 (V)                       @ 102,400,000  (51,200,000)
    //   (unused)                                         @ 153,600,000  ( 6,400,000)
    //   HIST/CURSOR: [200000] int                        @ 160,000,000  (   800,000)
    //   SUMS: [196] int (pad 4096)                       @ 160,800,000  (     4,096)
    //   SOFF: [196] int (pad 4096)                       @ 160,804,096  (     4,096)
    //   OFFS: [200001] int                               @ 160,808,192  (   800,004 pad->807,808)
    //   OBJS: [400000] int                               @ 161,616,000  ( 1,600,000)
    //   Ub:   [R][128][128] bf16                         @ 163,216,000  (   131,072)
    //   Wb:   [3][R][H][32][32] bf16                     @ 163,347,072  (    98,304)
    //   AGG:  [R*N][128] bf16                            @ 165,000,000  (51,200,000)
    char* ws = (char*)d_ws;
    ushort_t* BK  = (ushort_t*)(ws);
    ushort_t* BQ  = (ushort_t*)(ws + 51200000);
    ushort_t* BV  = (ushort_t*)(ws + 102400000);
    int*      HIST= (int*)     (ws + 160000000);   // doubles as CURSOR
    int*      SUMS= (int*)     (ws + 160800000);
    int*      SOFF= (int*)     (ws + 160804096);
    int*      OFFS= (int*)     (ws + 160808192);
    int*      OBJS= (int*)     (ws + 161616000);
    ushort_t* Ub  = (ushort_t*)(ws + 163216000);
    ushort_t* Wb  = (ushort_t*)(ws + 163347072);
    ushort_t* AGG = (ushort_t*)(ws + 165000000);

    // prep: casts + HIST zero (1 launch)
    prep_kernel<<<(N_ROWS + 255) / 256, 256, 0, stream>>>(tk, tq, tv, un, Wb, Ub, HIST);

    // CSR build
    hist_kernel<<<(N_EDGE + 255) / 256, 256, 0, stream>>>(esub, epred, HIST);
    scan_p1<<<196, 256, 0, stream>>>(HIST, SUMS);
    scan_p2<<<1, 256, 0, stream>>>(SUMS, SOFF, OFFS);
    scan_p3<<<196, 256, 0, stream>>>(HIST, SOFF, OFFS, HIST);  // OFFS + CURSOR (reuses HIST)
    scatter_kernel<<<(N_EDGE + 255) / 256, 256, 0, stream>>>(esub, epred, eobj, HIST, OBJS);

    // K/Q/V for all relations in one MFMA pass
    proj_mfma<<<(N_NODES + 127) / 128, 512, 0, stream>>>(x, Wb, BK, BQ, BV);

    // fused dot + softmax + aggregate
    agg_fused<<<N_ROWS / 4, 256, 0, stream>>>(OFFS, OBJS, BK, BQ, BV, AGG);

    unify_mfma<<<(N_NODES + 63) / 64, 256, 0, stream>>>(AGG, Ub, out);
}